// Round 1
// baseline (3062.234 us; speedup 1.0000x reference)
//
#include <hip/hip_runtime.h>

#define N_NODES 100000
#define N_EDGES 1600000

// Accumulate 16 outputs from one x value and four float4 weight chunks.
#define FMA16(A, xv) do { \
    A[0]  = fmaf((xv), wa.x, A[0]);  A[1]  = fmaf((xv), wa.y, A[1]);  \
    A[2]  = fmaf((xv), wa.z, A[2]);  A[3]  = fmaf((xv), wa.w, A[3]);  \
    A[4]  = fmaf((xv), wb.x, A[4]);  A[5]  = fmaf((xv), wb.y, A[5]);  \
    A[6]  = fmaf((xv), wb.z, A[6]);  A[7]  = fmaf((xv), wb.w, A[7]);  \
    A[8]  = fmaf((xv), wc.x, A[8]);  A[9]  = fmaf((xv), wc.y, A[9]);  \
    A[10] = fmaf((xv), wc.z, A[10]); A[11] = fmaf((xv), wc.w, A[11]); \
    A[12] = fmaf((xv), wd.x, A[12]); A[13] = fmaf((xv), wd.y, A[13]); \
    A[14] = fmaf((xv), wd.z, A[14]); A[15] = fmaf((xv), wd.w, A[15]); \
} while (0)

// ---------------------------------------------------------------------------
// Kernel A: 4 simultaneous node transforms  O_m = X @ W_m  (bias added to m==3)
// 32-node tile, 256 threads. LDS = 8.3KB xs + 64KB W = 72.3KB -> 2 blocks/CU.
// mat = tid>>6 is wave-uniform; W reads have only 4 distinct addrs/wave (free);
// xs reads: 16 distinct rows, stride-2 banks -> conflict-free.
// ---------------------------------------------------------------------------
__global__ __launch_bounds__(256) void transform4_kernel(
    const float* __restrict__ X,
    const float* __restrict__ W0, const float* __restrict__ W1,
    const float* __restrict__ W2, const float* __restrict__ W3,
    const float* __restrict__ B3,
    float* __restrict__ O0, float* __restrict__ O1,
    float* __restrict__ O2, float* __restrict__ O3)
{
    __shared__ float xs[32][65];
    __shared__ float ws[4][64][64];
    const int tid  = threadIdx.x;
    const int base = blockIdx.x * 32;

    {
        const float* Wp0 = W0; const float* Wp1 = W1;
        const float* Wp2 = W2; const float* Wp3 = W3;
        float4* d0 = (float4*)&ws[0][0][0];
        float4* d1 = (float4*)&ws[1][0][0];
        float4* d2 = (float4*)&ws[2][0][0];
        float4* d3 = (float4*)&ws[3][0][0];
        for (int i = tid; i < 1024; i += 256) {
            d0[i] = ((const float4*)Wp0)[i];
            d1[i] = ((const float4*)Wp1)[i];
            d2[i] = ((const float4*)Wp2)[i];
            d3[i] = ((const float4*)Wp3)[i];
        }
    }
    for (int i = tid; i < 512; i += 256) {
        int r = i >> 4, c = i & 15;
        int node = base + r;                 // 3125*32 == 100000, always in range
        float4 v = ((const float4*)X)[node * 16 + c];
        *(float4*)&xs[r][c * 4] = v;
    }
    __syncthreads();

    const int mat  = tid >> 6;      // wave-uniform
    const int lane = tid & 63;
    const int ng   = lane >> 2;     // 0..15 -> rows 2ng, 2ng+1
    const int og   = (lane & 3) * 16;

    float acc0[16], acc1[16];
    #pragma unroll
    for (int j = 0; j < 16; ++j) { acc0[j] = 0.f; acc1[j] = 0.f; }

    for (int k = 0; k < 64; ++k) {
        float4 wa = *(const float4*)&ws[mat][k][og + 0];
        float4 wb = *(const float4*)&ws[mat][k][og + 4];
        float4 wc = *(const float4*)&ws[mat][k][og + 8];
        float4 wd = *(const float4*)&ws[mat][k][og + 12];
        float x0 = xs[2 * ng + 0][k];
        float x1 = xs[2 * ng + 1][k];
        FMA16(acc0, x0);
        FMA16(acc1, x1);
    }

    float bias[16];
    #pragma unroll
    for (int j = 0; j < 16; ++j) bias[j] = (mat == 3) ? B3[og + j] : 0.f;

    float* O = (mat == 0) ? O0 : (mat == 1) ? O1 : (mat == 2) ? O2 : O3;
    #pragma unroll
    for (int i = 0; i < 2; ++i) {
        int node = base + 2 * ng + i;
        float* dst = O + node * 64 + og;
        const float* A = (i == 0) ? acc0 : acc1;
        *(float4*)(dst + 0)  = make_float4(A[0]  + bias[0],  A[1]  + bias[1],
                                           A[2]  + bias[2],  A[3]  + bias[3]);
        *(float4*)(dst + 4)  = make_float4(A[4]  + bias[4],  A[5]  + bias[5],
                                           A[6]  + bias[6],  A[7]  + bias[7]);
        *(float4*)(dst + 8)  = make_float4(A[8]  + bias[8],  A[9]  + bias[9],
                                           A[10] + bias[10], A[11] + bias[11]);
        *(float4*)(dst + 12) = make_float4(A[12] + bias[12], A[13] + bias[13],
                                           A[14] + bias[14], A[15] + bias[15]);
    }
}

// ---------------------------------------------------------------------------
// Kernel B: edge gather + sigmoid gate + atomic scatter-add.
// 16 lanes per edge, one float4 per lane (coalesced 256B gathers per edge).
// ---------------------------------------------------------------------------
__global__ __launch_bounds__(256) void edge_kernel(
    const float* __restrict__ K, const float* __restrict__ Q,
    const float* __restrict__ V, const int* __restrict__ EI,
    float* __restrict__ AGG)
{
    int gt = blockIdx.x * 256 + threadIdx.x;
    int e = gt >> 4;
    if (e >= N_EDGES) return;
    int c = (gt & 15) * 4;
    int s = __ldg(EI + e);
    int d = __ldg(EI + N_EDGES + e);

    float4 kv = *(const float4*)(K + d * 64 + c);
    float4 qv = *(const float4*)(Q + s * 64 + c);
    float4 vv = *(const float4*)(V + s * 64 + c);

    float4 m;
    m.x = vv.x / (1.f + __expf(-(kv.x + qv.x)));
    m.y = vv.y / (1.f + __expf(-(kv.y + qv.y)));
    m.z = vv.z / (1.f + __expf(-(kv.z + qv.z)));
    m.w = vv.w / (1.f + __expf(-(kv.w + qv.w)));

    float* a = AGG + d * 64 + c;
    atomicAdd(a + 0, m.x);
    atomicAdd(a + 1, m.y);
    atomicAdd(a + 2, m.z);
    atomicAdd(a + 3, m.w);
}

// ---------------------------------------------------------------------------
// Kernel C1: h = relu(agg @ Wl + bl) in LDS, then the four layer-2 transforms
// written in place over K,Q,V,AGG. 64-node tile. LDS ~113KB -> 1 block/CU.
// AGG_IN / O3 alias: no __restrict__ on them; loads complete before the first
// barrier, stores happen after, and each block only touches its own rows.
// ---------------------------------------------------------------------------
__global__ __launch_bounds__(256) void mid_kernel(
    const float* AGG_IN,
    const float* __restrict__ WL, const float* __restrict__ BL,
    const float* __restrict__ W0, const float* __restrict__ W1,
    const float* __restrict__ W2, const float* __restrict__ W3,
    const float* __restrict__ B3,
    float* __restrict__ O0, float* __restrict__ O1,
    float* __restrict__ O2, float* O3)
{
    __shared__ float xin[64][65];
    __shared__ float hs[64][65];
    __shared__ float wl[64][64];
    __shared__ float w2[4][64][64];
    const int tid  = threadIdx.x;
    const int base = blockIdx.x * 64;

    {
        float4* dl = (float4*)&wl[0][0];
        float4* d0 = (float4*)&w2[0][0][0];
        float4* d1 = (float4*)&w2[1][0][0];
        float4* d2 = (float4*)&w2[2][0][0];
        float4* d3 = (float4*)&w2[3][0][0];
        for (int i = tid; i < 1024; i += 256) {
            dl[i] = ((const float4*)WL)[i];
            d0[i] = ((const float4*)W0)[i];
            d1[i] = ((const float4*)W1)[i];
            d2[i] = ((const float4*)W2)[i];
            d3[i] = ((const float4*)W3)[i];
        }
    }
    for (int i = tid; i < 1024; i += 256) {
        int r = i >> 4, c = i & 15;
        int node = base + r;
        float4 v = make_float4(0.f, 0.f, 0.f, 0.f);
        if (node < N_NODES) v = ((const float4*)AGG_IN)[node * 16 + c];
        *(float4*)&xin[r][c * 4] = v;
    }
    __syncthreads();

    // stage 1: h = relu(xin @ WL + BL)
    {
        const int node = tid >> 2;
        const int og   = (tid & 3) * 16;
        float acc[16];
        #pragma unroll
        for (int j = 0; j < 16; ++j) acc[j] = 0.f;
        for (int k = 0; k < 64; ++k) {
            float4 wa = *(const float4*)&wl[k][og + 0];
            float4 wb = *(const float4*)&wl[k][og + 4];
            float4 wc = *(const float4*)&wl[k][og + 8];
            float4 wd = *(const float4*)&wl[k][og + 12];
            float xv = xin[node][k];
            FMA16(acc, xv);
        }
        #pragma unroll
        for (int j = 0; j < 16; ++j)
            hs[node][og + j] = fmaxf(acc[j] + BL[og + j], 0.f);
    }
    __syncthreads();

    // stage 2: four transforms of h
    const int mat  = tid >> 6;
    const int lane = tid & 63;
    const int ng   = lane >> 2;      // 0..15 -> 4 nodes each
    const int og   = (lane & 3) * 16;

    float a0[16], a1[16], a2[16], a3[16];
    #pragma unroll
    for (int j = 0; j < 16; ++j) { a0[j] = 0.f; a1[j] = 0.f; a2[j] = 0.f; a3[j] = 0.f; }

    for (int k = 0; k < 64; ++k) {
        float4 wa = *(const float4*)&w2[mat][k][og + 0];
        float4 wb = *(const float4*)&w2[mat][k][og + 4];
        float4 wc = *(const float4*)&w2[mat][k][og + 8];
        float4 wd = *(const float4*)&w2[mat][k][og + 12];
        float x0 = hs[4 * ng + 0][k];
        float x1 = hs[4 * ng + 1][k];
        float x2 = hs[4 * ng + 2][k];
        float x3 = hs[4 * ng + 3][k];
        FMA16(a0, x0);
        FMA16(a1, x1);
        FMA16(a2, x2);
        FMA16(a3, x3);
    }

    float bias[16];
    #pragma unroll
    for (int j = 0; j < 16; ++j) bias[j] = (mat == 3) ? B3[og + j] : 0.f;

    float* O = (mat == 0) ? O0 : (mat == 1) ? O1 : (mat == 2) ? O2 : O3;
    #pragma unroll
    for (int i = 0; i < 4; ++i) {
        int node = base + 4 * ng + i;
        if (node < N_NODES) {
            float* dst = O + node * 64 + og;
            const float* A = (i == 0) ? a0 : (i == 1) ? a1 : (i == 2) ? a2 : a3;
            *(float4*)(dst + 0)  = make_float4(A[0]  + bias[0],  A[1]  + bias[1],
                                               A[2]  + bias[2],  A[3]  + bias[3]);
            *(float4*)(dst + 4)  = make_float4(A[4]  + bias[4],  A[5]  + bias[5],
                                               A[6]  + bias[6],  A[7]  + bias[7]);
            *(float4*)(dst + 8)  = make_float4(A[8]  + bias[8],  A[9]  + bias[9],
                                               A[10] + bias[10], A[11] + bias[11]);
            *(float4*)(dst + 12) = make_float4(A[12] + bias[12], A[13] + bias[13],
                                               A[14] + bias[14], A[15] + bias[15]);
        }
    }
}

// ---------------------------------------------------------------------------
// Kernel C2: out = relu(agg @ Wl2 + bl2)
// ---------------------------------------------------------------------------
__global__ __launch_bounds__(256) void final_kernel(
    const float* __restrict__ AGG, const float* __restrict__ WL,
    const float* __restrict__ BL, float* __restrict__ OUT)
{
    __shared__ float xin[64][65];
    __shared__ float wl[64][64];
    const int tid  = threadIdx.x;
    const int base = blockIdx.x * 64;

    {
        float4* dl = (float4*)&wl[0][0];
        for (int i = tid; i < 1024; i += 256) dl[i] = ((const float4*)WL)[i];
    }
    for (int i = tid; i < 1024; i += 256) {
        int r = i >> 4, c = i & 15;
        int node = base + r;
        float4 v = make_float4(0.f, 0.f, 0.f, 0.f);
        if (node < N_NODES) v = ((const float4*)AGG)[node * 16 + c];
        *(float4*)&xin[r][c * 4] = v;
    }
    __syncthreads();

    const int node = tid >> 2;
    const int og   = (tid & 3) * 16;
    float acc[16];
    #pragma unroll
    for (int j = 0; j < 16; ++j) acc[j] = 0.f;
    for (int k = 0; k < 64; ++k) {
        float4 wa = *(const float4*)&wl[k][og + 0];
        float4 wb = *(const float4*)&wl[k][og + 4];
        float4 wc = *(const float4*)&wl[k][og + 8];
        float4 wd = *(const float4*)&wl[k][og + 12];
        float xv = xin[node][k];
        FMA16(acc, xv);
    }

    int out_node = base + node;
    if (out_node < N_NODES) {
        float* dst = OUT + out_node * 64 + og;
        float r0[16];
        #pragma unroll
        for (int j = 0; j < 16; ++j) r0[j] = fmaxf(acc[j] + BL[og + j], 0.f);
        *(float4*)(dst + 0)  = make_float4(r0[0],  r0[1],  r0[2],  r0[3]);
        *(float4*)(dst + 4)  = make_float4(r0[4],  r0[5],  r0[6],  r0[7]);
        *(float4*)(dst + 8)  = make_float4(r0[8],  r0[9],  r0[10], r0[11]);
        *(float4*)(dst + 12) = make_float4(r0[12], r0[13], r0[14], r0[15]);
    }
}

extern "C" void kernel_launch(void* const* d_in, const int* in_sizes, int n_in,
                              void* d_out, int out_size, void* d_ws, size_t ws_size,
                              hipStream_t stream)
{
    const float* x   = (const float*)d_in[0];
    const float* Wk1 = (const float*)d_in[1];
    const float* Wq1 = (const float*)d_in[2];
    const float* Wv1 = (const float*)d_in[3];
    const float* Ws1 = (const float*)d_in[4];
    const float* b1  = (const float*)d_in[5];
    const float* Wl1 = (const float*)d_in[6];
    const float* bl1 = (const float*)d_in[7];
    const float* Wk2 = (const float*)d_in[8];
    const float* Wq2 = (const float*)d_in[9];
    const float* Wv2 = (const float*)d_in[10];
    const float* Ws2 = (const float*)d_in[11];
    const float* b2  = (const float*)d_in[12];
    const float* Wl2 = (const float*)d_in[13];
    const float* bl2 = (const float*)d_in[14];
    const int*   ei  = (const int*)d_in[15];

    float* K   = (float*)d_ws;
    float* Q   = K + (size_t)N_NODES * 64;
    float* V   = Q + (size_t)N_NODES * 64;
    float* AGG = V + (size_t)N_NODES * 64;

    // Layer 1: node transforms (agg initialized with x@Ws1 + b1)
    transform4_kernel<<<3125, 256, 0, stream>>>(x, Wk1, Wq1, Wv1, Ws1, b1,
                                                K, Q, V, AGG);
    // Layer 1: edge phase
    edge_kernel<<<(N_EDGES * 16) / 256, 256, 0, stream>>>(K, Q, V, ei, AGG);
    // h = relu(agg@Wl1+bl1); layer-2 transforms in place
    mid_kernel<<<1563, 256, 0, stream>>>(AGG, Wl1, bl1,
                                         Wk2, Wq2, Wv2, Ws2, b2,
                                         K, Q, V, AGG);
    // Layer 2: edge phase
    edge_kernel<<<(N_EDGES * 16) / 256, 256, 0, stream>>>(K, Q, V, ei, AGG);
    // Output
    final_kernel<<<1563, 256, 0, stream>>>(AGG, Wl2, bl2, (float*)d_out);
}

// Round 2
// 729.286 us; speedup vs baseline: 4.1989x; 4.1989x over previous
//
#include <hip/hip_runtime.h>

#define N_NODES 100000
#define N_EDGES 1600000
#define SCAN_CHUNK 1024
#define SCAN_NB 98          // 98*1024 = 100352 >= N_NODES

// Accumulate 16 outputs from one x value and four float4 weight chunks.
#define FMA16(A, xv) do { \
    A[0]  = fmaf((xv), wa.x, A[0]);  A[1]  = fmaf((xv), wa.y, A[1]);  \
    A[2]  = fmaf((xv), wa.z, A[2]);  A[3]  = fmaf((xv), wa.w, A[3]);  \
    A[4]  = fmaf((xv), wb.x, A[4]);  A[5]  = fmaf((xv), wb.y, A[5]);  \
    A[6]  = fmaf((xv), wb.z, A[6]);  A[7]  = fmaf((xv), wb.w, A[7]);  \
    A[8]  = fmaf((xv), wc.x, A[8]);  A[9]  = fmaf((xv), wc.y, A[9]);  \
    A[10] = fmaf((xv), wc.z, A[10]); A[11] = fmaf((xv), wc.w, A[11]); \
    A[12] = fmaf((xv), wd.x, A[12]); A[13] = fmaf((xv), wd.y, A[13]); \
    A[14] = fmaf((xv), wd.z, A[14]); A[15] = fmaf((xv), wd.w, A[15]); \
} while (0)

// ---------------------------------------------------------------------------
// CSR build: histogram of in-degrees
// ---------------------------------------------------------------------------
__global__ __launch_bounds__(256) void hist_kernel(
    const int* __restrict__ EI, int* __restrict__ deg)
{
    int e = blockIdx.x * 256 + threadIdx.x;
    if (e < N_EDGES) atomicAdd(&deg[EI[N_EDGES + e]], 1);
}

// block-level sums of deg (1024 elems per block)
__global__ __launch_bounds__(1024) void scan_p1_kernel(
    const int* __restrict__ deg, int* __restrict__ bsum)
{
    __shared__ int s[1024];
    int tid = threadIdx.x;
    int i = blockIdx.x * SCAN_CHUNK + tid;
    s[tid] = (i < N_NODES) ? deg[i] : 0;
    __syncthreads();
    for (int off = 512; off > 0; off >>= 1) {
        if (tid < off) s[tid] += s[tid + off];
        __syncthreads();
    }
    if (tid == 0) bsum[blockIdx.x] = s[0];
}

// exclusive scan of the SCAN_NB block sums (single block)
__global__ __launch_bounds__(128) void scan_p2_kernel(
    const int* __restrict__ bsum, int* __restrict__ bbase)
{
    __shared__ int s[SCAN_NB];
    int tid = threadIdx.x;
    if (tid < SCAN_NB) s[tid] = bsum[tid];
    __syncthreads();
    if (tid == 0) {
        int run = 0;
        for (int i = 0; i < SCAN_NB; ++i) { int t = s[i]; s[i] = run; run += t; }
    }
    __syncthreads();
    if (tid < SCAN_NB) bbase[tid] = s[tid];
}

// per-block inclusive scan (Hillis-Steele) -> exclusive start offsets
__global__ __launch_bounds__(1024) void scan_p3_kernel(
    const int* __restrict__ deg, const int* __restrict__ bbase,
    int* __restrict__ start)
{
    __shared__ int s[1024];
    int tid = threadIdx.x;
    int i = blockIdx.x * SCAN_CHUNK + tid;
    int v = (i < N_NODES) ? deg[i] : 0;
    s[tid] = v;
    __syncthreads();
    for (int off = 1; off < 1024; off <<= 1) {
        int t = (tid >= off) ? s[tid - off] : 0;
        __syncthreads();
        s[tid] += t;
        __syncthreads();
    }
    if (i < N_NODES) start[i] = bbase[blockIdx.x] + s[tid] - v;
}

// scatter src ids into dst-sorted order
__global__ __launch_bounds__(256) void scatter_kernel(
    const int* __restrict__ EI, const int* __restrict__ start,
    int* __restrict__ cur, int* __restrict__ ssrc)
{
    int e = blockIdx.x * 256 + threadIdx.x;
    if (e < N_EDGES) {
        int s = EI[e];
        int d = EI[N_EDGES + e];
        int pos = start[d] + atomicAdd(&cur[d], 1);
        ssrc[pos] = s;
    }
}

// ---------------------------------------------------------------------------
// Kernel A: 4 simultaneous node transforms  O_m = X @ W_m  (bias added to m==3)
// ---------------------------------------------------------------------------
__global__ __launch_bounds__(256) void transform4_kernel(
    const float* __restrict__ X,
    const float* __restrict__ W0, const float* __restrict__ W1,
    const float* __restrict__ W2, const float* __restrict__ W3,
    const float* __restrict__ B3,
    float* __restrict__ O0, float* __restrict__ O1,
    float* __restrict__ O2, float* __restrict__ O3)
{
    __shared__ float xs[32][65];
    __shared__ float ws[4][64][64];
    const int tid  = threadIdx.x;
    const int base = blockIdx.x * 32;

    {
        float4* d0 = (float4*)&ws[0][0][0];
        float4* d1 = (float4*)&ws[1][0][0];
        float4* d2 = (float4*)&ws[2][0][0];
        float4* d3 = (float4*)&ws[3][0][0];
        for (int i = tid; i < 1024; i += 256) {
            d0[i] = ((const float4*)W0)[i];
            d1[i] = ((const float4*)W1)[i];
            d2[i] = ((const float4*)W2)[i];
            d3[i] = ((const float4*)W3)[i];
        }
    }
    for (int i = tid; i < 512; i += 256) {
        int r = i >> 4, c = i & 15;
        int node = base + r;                 // 3125*32 == 100000, always in range
        float4 v = ((const float4*)X)[node * 16 + c];
        *(float4*)&xs[r][c * 4] = v;
    }
    __syncthreads();

    const int mat  = tid >> 6;      // wave-uniform
    const int lane = tid & 63;
    const int ng   = lane >> 2;     // 0..15 -> rows 2ng, 2ng+1
    const int og   = (lane & 3) * 16;

    float acc0[16], acc1[16];
    #pragma unroll
    for (int j = 0; j < 16; ++j) { acc0[j] = 0.f; acc1[j] = 0.f; }

    for (int k = 0; k < 64; ++k) {
        float4 wa = *(const float4*)&ws[mat][k][og + 0];
        float4 wb = *(const float4*)&ws[mat][k][og + 4];
        float4 wc = *(const float4*)&ws[mat][k][og + 8];
        float4 wd = *(const float4*)&ws[mat][k][og + 12];
        float x0 = xs[2 * ng + 0][k];
        float x1 = xs[2 * ng + 1][k];
        FMA16(acc0, x0);
        FMA16(acc1, x1);
    }

    float bias[16];
    #pragma unroll
    for (int j = 0; j < 16; ++j) bias[j] = (mat == 3) ? B3[og + j] : 0.f;

    float* O = (mat == 0) ? O0 : (mat == 1) ? O1 : (mat == 2) ? O2 : O3;
    #pragma unroll
    for (int i = 0; i < 2; ++i) {
        int node = base + 2 * ng + i;
        float* dst = O + node * 64 + og;
        const float* A = (i == 0) ? acc0 : acc1;
        *(float4*)(dst + 0)  = make_float4(A[0]  + bias[0],  A[1]  + bias[1],
                                           A[2]  + bias[2],  A[3]  + bias[3]);
        *(float4*)(dst + 4)  = make_float4(A[4]  + bias[4],  A[5]  + bias[5],
                                           A[6]  + bias[6],  A[7]  + bias[7]);
        *(float4*)(dst + 8)  = make_float4(A[8]  + bias[8],  A[9]  + bias[9],
                                           A[10] + bias[10], A[11] + bias[11]);
        *(float4*)(dst + 12) = make_float4(A[12] + bias[12], A[13] + bias[13],
                                           A[14] + bias[14], A[15] + bias[15]);
    }
}

// ---------------------------------------------------------------------------
// Kernel B: atomic-free aggregation. One wave per node; 4 edge slots x 16
// column lanes. Gathers q[src]/v[src] as coalesced 256B rows, reduces across
// edge slots with shfl_xor, single rmw of agg[n].
// ---------------------------------------------------------------------------
__global__ __launch_bounds__(256) void agg_kernel(
    const float* __restrict__ K, const float* __restrict__ Q,
    const float* __restrict__ V, const int* __restrict__ start,
    const int* __restrict__ deg, const int* __restrict__ ssrc,
    float* __restrict__ AGG)
{
    int n = (blockIdx.x * 256 + threadIdx.x) >> 6;   // grid sized exactly
    int lane = threadIdx.x & 63;
    int eg = lane >> 4;            // edge slot 0..3
    int c  = (lane & 15) * 4;      // column group

    const float4 kv = *(const float4*)(K + (size_t)n * 64 + c);
    float4 acc = make_float4(0.f, 0.f, 0.f, 0.f);

    int s0 = start[n];
    int dn = deg[n];
    for (int p = eg; p < dn; p += 4) {
        int s = ssrc[s0 + p];
        float4 qv = *(const float4*)(Q + (size_t)s * 64 + c);
        float4 vv = *(const float4*)(V + (size_t)s * 64 + c);
        acc.x += vv.x / (1.f + __expf(-(kv.x + qv.x)));
        acc.y += vv.y / (1.f + __expf(-(kv.y + qv.y)));
        acc.z += vv.z / (1.f + __expf(-(kv.z + qv.z)));
        acc.w += vv.w / (1.f + __expf(-(kv.w + qv.w)));
    }

    // reduce across the 4 edge slots (lanes differing in bits 4,5)
    acc.x += __shfl_xor(acc.x, 16); acc.y += __shfl_xor(acc.y, 16);
    acc.z += __shfl_xor(acc.z, 16); acc.w += __shfl_xor(acc.w, 16);
    acc.x += __shfl_xor(acc.x, 32); acc.y += __shfl_xor(acc.y, 32);
    acc.z += __shfl_xor(acc.z, 32); acc.w += __shfl_xor(acc.w, 32);

    if (eg == 0) {
        float4* a = (float4*)(AGG + (size_t)n * 64 + c);
        float4 o = *a;
        o.x += acc.x; o.y += acc.y; o.z += acc.z; o.w += acc.w;
        *a = o;
    }
}

// ---------------------------------------------------------------------------
// Kernel C1: h = relu(agg @ Wl + bl) in LDS, then the four layer-2 transforms
// written in place over K,Q,V,AGG.
// ---------------------------------------------------------------------------
__global__ __launch_bounds__(256) void mid_kernel(
    const float* AGG_IN,
    const float* __restrict__ WL, const float* __restrict__ BL,
    const float* __restrict__ W0, const float* __restrict__ W1,
    const float* __restrict__ W2, const float* __restrict__ W3,
    const float* __restrict__ B3,
    float* __restrict__ O0, float* __restrict__ O1,
    float* __restrict__ O2, float* O3)
{
    __shared__ float xin[64][65];
    __shared__ float hs[64][65];
    __shared__ float wl[64][64];
    __shared__ float w2[4][64][64];
    const int tid  = threadIdx.x;
    const int base = blockIdx.x * 64;

    {
        float4* dl = (float4*)&wl[0][0];
        float4* d0 = (float4*)&w2[0][0][0];
        float4* d1 = (float4*)&w2[1][0][0];
        float4* d2 = (float4*)&w2[2][0][0];
        float4* d3 = (float4*)&w2[3][0][0];
        for (int i = tid; i < 1024; i += 256) {
            dl[i] = ((const float4*)WL)[i];
            d0[i] = ((const float4*)W0)[i];
            d1[i] = ((const float4*)W1)[i];
            d2[i] = ((const float4*)W2)[i];
            d3[i] = ((const float4*)W3)[i];
        }
    }
    for (int i = tid; i < 1024; i += 256) {
        int r = i >> 4, c = i & 15;
        int node = base + r;
        float4 v = make_float4(0.f, 0.f, 0.f, 0.f);
        if (node < N_NODES) v = ((const float4*)AGG_IN)[node * 16 + c];
        *(float4*)&xin[r][c * 4] = v;
    }
    __syncthreads();

    // stage 1: h = relu(xin @ WL + BL)
    {
        const int node = tid >> 2;
        const int og   = (tid & 3) * 16;
        float acc[16];
        #pragma unroll
        for (int j = 0; j < 16; ++j) acc[j] = 0.f;
        for (int k = 0; k < 64; ++k) {
            float4 wa = *(const float4*)&wl[k][og + 0];
            float4 wb = *(const float4*)&wl[k][og + 4];
            float4 wc = *(const float4*)&wl[k][og + 8];
            float4 wd = *(const float4*)&wl[k][og + 12];
            float xv = xin[node][k];
            FMA16(acc, xv);
        }
        #pragma unroll
        for (int j = 0; j < 16; ++j)
            hs[node][og + j] = fmaxf(acc[j] + BL[og + j], 0.f);
    }
    __syncthreads();

    // stage 2: four transforms of h
    const int mat  = tid >> 6;
    const int lane = tid & 63;
    const int ng   = lane >> 2;      // 0..15 -> 4 nodes each
    const int og   = (lane & 3) * 16;

    float a0[16], a1[16], a2[16], a3[16];
    #pragma unroll
    for (int j = 0; j < 16; ++j) { a0[j] = 0.f; a1[j] = 0.f; a2[j] = 0.f; a3[j] = 0.f; }

    for (int k = 0; k < 64; ++k) {
        float4 wa = *(const float4*)&w2[mat][k][og + 0];
        float4 wb = *(const float4*)&w2[mat][k][og + 4];
        float4 wc = *(const float4*)&w2[mat][k][og + 8];
        float4 wd = *(const float4*)&w2[mat][k][og + 12];
        float x0 = hs[4 * ng + 0][k];
        float x1 = hs[4 * ng + 1][k];
        float x2 = hs[4 * ng + 2][k];
        float x3 = hs[4 * ng + 3][k];
        FMA16(a0, x0);
        FMA16(a1, x1);
        FMA16(a2, x2);
        FMA16(a3, x3);
    }

    float bias[16];
    #pragma unroll
    for (int j = 0; j < 16; ++j) bias[j] = (mat == 3) ? B3[og + j] : 0.f;

    float* O = (mat == 0) ? O0 : (mat == 1) ? O1 : (mat == 2) ? O2 : O3;
    #pragma unroll
    for (int i = 0; i < 4; ++i) {
        int node = base + 4 * ng + i;
        if (node < N_NODES) {
            float* dst = O + node * 64 + og;
            const float* A = (i == 0) ? a0 : (i == 1) ? a1 : (i == 2) ? a2 : a3;
            *(float4*)(dst + 0)  = make_float4(A[0]  + bias[0],  A[1]  + bias[1],
                                               A[2]  + bias[2],  A[3]  + bias[3]);
            *(float4*)(dst + 4)  = make_float4(A[4]  + bias[4],  A[5]  + bias[5],
                                               A[6]  + bias[6],  A[7]  + bias[7]);
            *(float4*)(dst + 8)  = make_float4(A[8]  + bias[8],  A[9]  + bias[9],
                                               A[10] + bias[10], A[11] + bias[11]);
            *(float4*)(dst + 12) = make_float4(A[12] + bias[12], A[13] + bias[13],
                                               A[14] + bias[14], A[15] + bias[15]);
        }
    }
}

// ---------------------------------------------------------------------------
// Kernel C2: out = relu(agg @ Wl2 + bl2)
// ---------------------------------------------------------------------------
__global__ __launch_bounds__(256) void final_kernel(
    const float* __restrict__ AGG, const float* __restrict__ WL,
    const float* __restrict__ BL, float* __restrict__ OUT)
{
    __shared__ float xin[64][65];
    __shared__ float wl[64][64];
    const int tid  = threadIdx.x;
    const int base = blockIdx.x * 64;

    {
        float4* dl = (float4*)&wl[0][0];
        for (int i = tid; i < 1024; i += 256) dl[i] = ((const float4*)WL)[i];
    }
    for (int i = tid; i < 1024; i += 256) {
        int r = i >> 4, c = i & 15;
        int node = base + r;
        float4 v = make_float4(0.f, 0.f, 0.f, 0.f);
        if (node < N_NODES) v = ((const float4*)AGG)[node * 16 + c];
        *(float4*)&xin[r][c * 4] = v;
    }
    __syncthreads();

    const int node = tid >> 2;
    const int og   = (tid & 3) * 16;
    float acc[16];
    #pragma unroll
    for (int j = 0; j < 16; ++j) acc[j] = 0.f;
    for (int k = 0; k < 64; ++k) {
        float4 wa = *(const float4*)&wl[k][og + 0];
        float4 wb = *(const float4*)&wl[k][og + 4];
        float4 wc = *(const float4*)&wl[k][og + 8];
        float4 wd = *(const float4*)&wl[k][og + 12];
        float xv = xin[node][k];
        FMA16(acc, xv);
    }

    int out_node = base + node;
    if (out_node < N_NODES) {
        float* dst = OUT + out_node * 64 + og;
        float r0[16];
        #pragma unroll
        for (int j = 0; j < 16; ++j) r0[j] = fmaxf(acc[j] + BL[og + j], 0.f);
        *(float4*)(dst + 0)  = make_float4(r0[0],  r0[1],  r0[2],  r0[3]);
        *(float4*)(dst + 4)  = make_float4(r0[4],  r0[5],  r0[6],  r0[7]);
        *(float4*)(dst + 8)  = make_float4(r0[8],  r0[9],  r0[10], r0[11]);
        *(float4*)(dst + 12) = make_float4(r0[12], r0[13], r0[14], r0[15]);
    }
}

extern "C" void kernel_launch(void* const* d_in, const int* in_sizes, int n_in,
                              void* d_out, int out_size, void* d_ws, size_t ws_size,
                              hipStream_t stream)
{
    const float* x   = (const float*)d_in[0];
    const float* Wk1 = (const float*)d_in[1];
    const float* Wq1 = (const float*)d_in[2];
    const float* Wv1 = (const float*)d_in[3];
    const float* Ws1 = (const float*)d_in[4];
    const float* b1  = (const float*)d_in[5];
    const float* Wl1 = (const float*)d_in[6];
    const float* bl1 = (const float*)d_in[7];
    const float* Wk2 = (const float*)d_in[8];
    const float* Wq2 = (const float*)d_in[9];
    const float* Wv2 = (const float*)d_in[10];
    const float* Ws2 = (const float*)d_in[11];
    const float* b2  = (const float*)d_in[12];
    const float* Wl2 = (const float*)d_in[13];
    const float* bl2 = (const float*)d_in[14];
    const int*   ei  = (const int*)d_in[15];

    float* K   = (float*)d_ws;
    float* Q   = K + (size_t)N_NODES * 64;
    float* V   = Q + (size_t)N_NODES * 64;
    float* AGG = V + (size_t)N_NODES * 64;
    int* deg   = (int*)(AGG + (size_t)N_NODES * 64);
    int* cur   = deg + 100352;
    int* bsum  = cur + 100352;
    int* bbase = bsum + 128;
    int* start = bbase + 128;
    int* ssrc  = start + 100352;

    // --- CSR build (deg & cur are contiguous -> one memset) ---
    hipMemsetAsync(deg, 0, 2 * 100352 * sizeof(int), stream);
    hist_kernel<<<(N_EDGES + 255) / 256, 256, 0, stream>>>(ei, deg);
    scan_p1_kernel<<<SCAN_NB, 1024, 0, stream>>>(deg, bsum);
    scan_p2_kernel<<<1, 128, 0, stream>>>(bsum, bbase);
    scan_p3_kernel<<<SCAN_NB, 1024, 0, stream>>>(deg, bbase, start);
    scatter_kernel<<<(N_EDGES + 255) / 256, 256, 0, stream>>>(ei, start, cur, ssrc);

    // --- Layer 1 ---
    transform4_kernel<<<3125, 256, 0, stream>>>(x, Wk1, Wq1, Wv1, Ws1, b1,
                                                K, Q, V, AGG);
    agg_kernel<<<N_NODES / 4, 256, 0, stream>>>(K, Q, V, start, deg, ssrc, AGG);
    // h = relu(agg@Wl1+bl1); layer-2 transforms in place
    mid_kernel<<<1563, 256, 0, stream>>>(AGG, Wl1, bl1,
                                         Wk2, Wq2, Wv2, Ws2, b2,
                                         K, Q, V, AGG);
    // --- Layer 2 ---
    agg_kernel<<<N_NODES / 4, 256, 0, stream>>>(K, Q, V, start, deg, ssrc, AGG);
    final_kernel<<<1563, 256, 0, stream>>>(AGG, Wl2, bl2, (float*)d_out);
}

// Round 3
// 603.266 us; speedup vs baseline: 5.0761x; 1.2089x over previous
//
#include <hip/hip_runtime.h>

#define N_NODES 100000
#define N_EDGES 1600000
#define SCAN_CHUNK 1024
#define SCAN_NB 98          // 98*1024 = 100352 >= N_NODES

typedef unsigned short ushort_t;
typedef unsigned int uint_t;

static __device__ __forceinline__ ushort_t bf16_rne(float f) {
    uint_t u = __float_as_uint(f);
    u = (u + 0x7FFFu + ((u >> 16) & 1u)) >> 16;
    return (ushort_t)u;
}
static __device__ __forceinline__ uint_t bfpack(float lo, float hi) {
    return (uint_t)bf16_rne(lo) | ((uint_t)bf16_rne(hi) << 16);
}
static __device__ __forceinline__ float bf2f(ushort_t h) {
    return __uint_as_float(((uint_t)h) << 16);
}

// Accumulate 16 outputs from one x value and four float4 weight chunks.
#define FMA16(A, xv) do { \
    A[0]  = fmaf((xv), wa.x, A[0]);  A[1]  = fmaf((xv), wa.y, A[1]);  \
    A[2]  = fmaf((xv), wa.z, A[2]);  A[3]  = fmaf((xv), wa.w, A[3]);  \
    A[4]  = fmaf((xv), wb.x, A[4]);  A[5]  = fmaf((xv), wb.y, A[5]);  \
    A[6]  = fmaf((xv), wb.z, A[6]);  A[7]  = fmaf((xv), wb.w, A[7]);  \
    A[8]  = fmaf((xv), wc.x, A[8]);  A[9]  = fmaf((xv), wc.y, A[9]);  \
    A[10] = fmaf((xv), wc.z, A[10]); A[11] = fmaf((xv), wc.w, A[11]); \
    A[12] = fmaf((xv), wd.x, A[12]); A[13] = fmaf((xv), wd.y, A[13]); \
    A[14] = fmaf((xv), wd.z, A[14]); A[15] = fmaf((xv), wd.w, A[15]); \
} while (0)

// ---------------------------------------------------------------------------
// CSR build
// ---------------------------------------------------------------------------
__global__ __launch_bounds__(256) void hist_kernel(
    const int* __restrict__ EI, int* __restrict__ deg)
{
    int e = blockIdx.x * 256 + threadIdx.x;
    if (e < N_EDGES) atomicAdd(&deg[EI[N_EDGES + e]], 1);
}

__global__ __launch_bounds__(1024) void scan_p1_kernel(
    const int* __restrict__ deg, int* __restrict__ bsum)
{
    __shared__ int s[1024];
    int tid = threadIdx.x;
    int i = blockIdx.x * SCAN_CHUNK + tid;
    s[tid] = (i < N_NODES) ? deg[i] : 0;
    __syncthreads();
    for (int off = 512; off > 0; off >>= 1) {
        if (tid < off) s[tid] += s[tid + off];
        __syncthreads();
    }
    if (tid == 0) bsum[blockIdx.x] = s[0];
}

__global__ __launch_bounds__(128) void scan_p2_kernel(
    const int* __restrict__ bsum, int* __restrict__ bbase)
{
    __shared__ int s[SCAN_NB];
    int tid = threadIdx.x;
    if (tid < SCAN_NB) s[tid] = bsum[tid];
    __syncthreads();
    if (tid == 0) {
        int run = 0;
        for (int i = 0; i < SCAN_NB; ++i) { int t = s[i]; s[i] = run; run += t; }
    }
    __syncthreads();
    if (tid < SCAN_NB) bbase[tid] = s[tid];
}

__global__ __launch_bounds__(1024) void scan_p3_kernel(
    const int* __restrict__ deg, const int* __restrict__ bbase,
    int* __restrict__ start)
{
    __shared__ int s[1024];
    int tid = threadIdx.x;
    int i = blockIdx.x * SCAN_CHUNK + tid;
    int v = (i < N_NODES) ? deg[i] : 0;
    s[tid] = v;
    __syncthreads();
    for (int off = 1; off < 1024; off <<= 1) {
        int t = (tid >= off) ? s[tid - off] : 0;
        __syncthreads();
        s[tid] += t;
        __syncthreads();
    }
    if (i < N_NODES) start[i] = bbase[blockIdx.x] + s[tid] - v;
}

__global__ __launch_bounds__(256) void scatter_kernel(
    const int* __restrict__ EI, const int* __restrict__ start,
    int* __restrict__ cur, int* __restrict__ ssrc)
{
    int e = blockIdx.x * 256 + threadIdx.x;
    if (e < N_EDGES) {
        int s = EI[e];
        int d = EI[N_EDGES + e];
        int pos = start[d] + atomicAdd(&cur[d], 1);
        ssrc[pos] = s;
    }
}

// ---------------------------------------------------------------------------
// Kernel A: 4 simultaneous node transforms of X (fp32, 64 cols).
//   mat 0 -> K   (fp32)
//   mat 1 -> Qh  (bf16)
//   mat 2 -> Vh  (bf16)
//   mat 3 -> AGG (fp32, + bias B3)   [skip-connection init]
// 32-node tile, 256 threads, LDS 72.3KB -> 2 blocks/CU.
// ---------------------------------------------------------------------------
__global__ __launch_bounds__(256) void transform4_kernel(
    const float* __restrict__ X,
    const float* __restrict__ W0, const float* __restrict__ W1,
    const float* __restrict__ W2, const float* __restrict__ W3,
    const float* __restrict__ B3,
    float* __restrict__ K, ushort_t* __restrict__ Qh,
    ushort_t* __restrict__ Vh, float* __restrict__ AGG)
{
    __shared__ float xs[32][65];
    __shared__ float ws[4][64][64];
    const int tid  = threadIdx.x;
    const int base = blockIdx.x * 32;

    {
        float4* d0 = (float4*)&ws[0][0][0];
        float4* d1 = (float4*)&ws[1][0][0];
        float4* d2 = (float4*)&ws[2][0][0];
        float4* d3 = (float4*)&ws[3][0][0];
        for (int i = tid; i < 1024; i += 256) {
            d0[i] = ((const float4*)W0)[i];
            d1[i] = ((const float4*)W1)[i];
            d2[i] = ((const float4*)W2)[i];
            d3[i] = ((const float4*)W3)[i];
        }
    }
    for (int i = tid; i < 512; i += 256) {
        int r = i >> 4, c = i & 15;
        int node = base + r;                 // 3125*32 == 100000, in range
        float4 v = ((const float4*)X)[node * 16 + c];
        *(float4*)&xs[r][c * 4] = v;
    }
    __syncthreads();

    const int mat  = tid >> 6;      // wave-uniform
    const int lane = tid & 63;
    const int ng   = lane >> 2;     // rows 2ng, 2ng+1
    const int og   = (lane & 3) * 16;

    float acc0[16], acc1[16];
    #pragma unroll
    for (int j = 0; j < 16; ++j) { acc0[j] = 0.f; acc1[j] = 0.f; }

    for (int k = 0; k < 64; ++k) {
        float4 wa = *(const float4*)&ws[mat][k][og + 0];
        float4 wb = *(const float4*)&ws[mat][k][og + 4];
        float4 wc = *(const float4*)&ws[mat][k][og + 8];
        float4 wd = *(const float4*)&ws[mat][k][og + 12];
        float x0 = xs[2 * ng + 0][k];
        float x1 = xs[2 * ng + 1][k];
        FMA16(acc0, x0);
        FMA16(acc1, x1);
    }

    if (mat == 0 || mat == 3) {
        float bias[16];
        #pragma unroll
        for (int j = 0; j < 16; ++j) bias[j] = (mat == 3) ? B3[og + j] : 0.f;
        float* O = (mat == 0) ? K : AGG;
        #pragma unroll
        for (int i = 0; i < 2; ++i) {
            int node = base + 2 * ng + i;
            float* dst = O + (size_t)node * 64 + og;
            const float* A = (i == 0) ? acc0 : acc1;
            *(float4*)(dst + 0)  = make_float4(A[0]  + bias[0],  A[1]  + bias[1],
                                               A[2]  + bias[2],  A[3]  + bias[3]);
            *(float4*)(dst + 4)  = make_float4(A[4]  + bias[4],  A[5]  + bias[5],
                                               A[6]  + bias[6],  A[7]  + bias[7]);
            *(float4*)(dst + 8)  = make_float4(A[8]  + bias[8],  A[9]  + bias[9],
                                               A[10] + bias[10], A[11] + bias[11]);
            *(float4*)(dst + 12) = make_float4(A[12] + bias[12], A[13] + bias[13],
                                               A[14] + bias[14], A[15] + bias[15]);
        }
    } else {
        ushort_t* O = (mat == 1) ? Qh : Vh;
        #pragma unroll
        for (int i = 0; i < 2; ++i) {
            int node = base + 2 * ng + i;
            uint_t* dst = (uint_t*)(O + (size_t)node * 64 + og);
            const float* A = (i == 0) ? acc0 : acc1;
            uint4 u0, u1;
            u0.x = bfpack(A[0],  A[1]);  u0.y = bfpack(A[2],  A[3]);
            u0.z = bfpack(A[4],  A[5]);  u0.w = bfpack(A[6],  A[7]);
            u1.x = bfpack(A[8],  A[9]);  u1.y = bfpack(A[10], A[11]);
            u1.z = bfpack(A[12], A[13]); u1.w = bfpack(A[14], A[15]);
            *(uint4*)(dst + 0) = u0;
            *(uint4*)(dst + 4) = u1;
        }
    }
}

// ---------------------------------------------------------------------------
// Kernel B: atomic-free aggregation, bf16 gathers.
// One wave per node; 4 edge slots x 16 column lanes; each lane gathers 8B of
// q[src] and 8B of v[src] (128B coalesced per edge per array).
// ---------------------------------------------------------------------------
__global__ __launch_bounds__(256) void agg_kernel(
    const float* __restrict__ K, const ushort_t* __restrict__ Qh,
    const ushort_t* __restrict__ Vh, const int* __restrict__ start,
    const int* __restrict__ deg, const int* __restrict__ ssrc,
    float* __restrict__ AGG)
{
    int n = (blockIdx.x * 256 + threadIdx.x) >> 6;   // grid sized exactly
    int lane = threadIdx.x & 63;
    int eg = lane >> 4;            // edge slot 0..3
    int c  = (lane & 15) * 4;      // column group

    const float4 kv = *(const float4*)(K + (size_t)n * 64 + c);
    float4 acc = make_float4(0.f, 0.f, 0.f, 0.f);

    int s0 = start[n];
    int dn = deg[n];
    for (int p = eg; p < dn; p += 4) {
        int s = ssrc[s0 + p];
        ushort4 qh = *(const ushort4*)(Qh + (size_t)s * 64 + c);
        ushort4 vh = *(const ushort4*)(Vh + (size_t)s * 64 + c);
        acc.x += bf2f(vh.x) / (1.f + __expf(-(kv.x + bf2f(qh.x))));
        acc.y += bf2f(vh.y) / (1.f + __expf(-(kv.y + bf2f(qh.y))));
        acc.z += bf2f(vh.z) / (1.f + __expf(-(kv.z + bf2f(qh.z))));
        acc.w += bf2f(vh.w) / (1.f + __expf(-(kv.w + bf2f(qh.w))));
    }

    // reduce across the 4 edge slots (lanes differing in bits 4,5)
    acc.x += __shfl_xor(acc.x, 16); acc.y += __shfl_xor(acc.y, 16);
    acc.z += __shfl_xor(acc.z, 16); acc.w += __shfl_xor(acc.w, 16);
    acc.x += __shfl_xor(acc.x, 32); acc.y += __shfl_xor(acc.y, 32);
    acc.z += __shfl_xor(acc.z, 32); acc.w += __shfl_xor(acc.w, 32);

    if (eg == 0) {
        float4* a = (float4*)(AGG + (size_t)n * 64 + c);
        float4 o = *a;
        o.x += acc.x; o.y += acc.y; o.z += acc.z; o.w += acc.w;
        *a = o;
    }
}

// ---------------------------------------------------------------------------
// Kernel C: out = relu(agg @ Wl + bl).  33KB LDS -> 4 blocks/CU.
// Used for both the mid activation (-> H) and the final output (-> d_out).
// ---------------------------------------------------------------------------
__global__ __launch_bounds__(256) void relu_gemm_kernel(
    const float* __restrict__ AGG, const float* __restrict__ WL,
    const float* __restrict__ BL, float* __restrict__ OUT)
{
    __shared__ float xin[64][65];
    __shared__ float wl[64][64];
    const int tid  = threadIdx.x;
    const int base = blockIdx.x * 64;

    {
        float4* dl = (float4*)&wl[0][0];
        for (int i = tid; i < 1024; i += 256) dl[i] = ((const float4*)WL)[i];
    }
    for (int i = tid; i < 1024; i += 256) {
        int r = i >> 4, c = i & 15;
        int node = base + r;
        float4 v = make_float4(0.f, 0.f, 0.f, 0.f);
        if (node < N_NODES) v = ((const float4*)AGG)[node * 16 + c];
        *(float4*)&xin[r][c * 4] = v;
    }
    __syncthreads();

    const int node = tid >> 2;
    const int og   = (tid & 3) * 16;
    float acc[16];
    #pragma unroll
    for (int j = 0; j < 16; ++j) acc[j] = 0.f;
    for (int k = 0; k < 64; ++k) {
        float4 wa = *(const float4*)&wl[k][og + 0];
        float4 wb = *(const float4*)&wl[k][og + 4];
        float4 wc = *(const float4*)&wl[k][og + 8];
        float4 wd = *(const float4*)&wl[k][og + 12];
        float xv = xin[node][k];
        FMA16(acc, xv);
    }

    int out_node = base + node;
    if (out_node < N_NODES) {
        float* dst = OUT + (size_t)out_node * 64 + og;
        float r0[16];
        #pragma unroll
        for (int j = 0; j < 16; ++j) r0[j] = fmaxf(acc[j] + BL[og + j], 0.f);
        *(float4*)(dst + 0)  = make_float4(r0[0],  r0[1],  r0[2],  r0[3]);
        *(float4*)(dst + 4)  = make_float4(r0[4],  r0[5],  r0[6],  r0[7]);
        *(float4*)(dst + 8)  = make_float4(r0[8],  r0[9],  r0[10], r0[11]);
        *(float4*)(dst + 12) = make_float4(r0[12], r0[13], r0[14], r0[15]);
    }
}

extern "C" void kernel_launch(void* const* d_in, const int* in_sizes, int n_in,
                              void* d_out, int out_size, void* d_ws, size_t ws_size,
                              hipStream_t stream)
{
    const float* x   = (const float*)d_in[0];
    const float* Wk1 = (const float*)d_in[1];
    const float* Wq1 = (const float*)d_in[2];
    const float* Wv1 = (const float*)d_in[3];
    const float* Ws1 = (const float*)d_in[4];
    const float* b1  = (const float*)d_in[5];
    const float* Wl1 = (const float*)d_in[6];
    const float* bl1 = (const float*)d_in[7];
    const float* Wk2 = (const float*)d_in[8];
    const float* Wq2 = (const float*)d_in[9];
    const float* Wv2 = (const float*)d_in[10];
    const float* Ws2 = (const float*)d_in[11];
    const float* b2  = (const float*)d_in[12];
    const float* Wl2 = (const float*)d_in[13];
    const float* bl2 = (const float*)d_in[14];
    const int*   ei  = (const int*)d_in[15];

    const size_t NF = (size_t)N_NODES * 64;
    float*    K   = (float*)d_ws;
    float*    AGG = K + NF;
    float*    H   = AGG + NF;
    ushort_t* Qh  = (ushort_t*)(H + NF);
    ushort_t* Vh  = Qh + NF;
    int* deg   = (int*)(Vh + NF);
    int* cur   = deg + 100352;
    int* bsum  = cur + 100352;
    int* bbase = bsum + 128;
    int* start = bbase + 128;
    int* ssrc  = start + 100352;

    // --- CSR build (deg & cur contiguous -> one memset) ---
    hipMemsetAsync(deg, 0, 2 * 100352 * sizeof(int), stream);
    hist_kernel<<<(N_EDGES + 255) / 256, 256, 0, stream>>>(ei, deg);
    scan_p1_kernel<<<SCAN_NB, 1024, 0, stream>>>(deg, bsum);
    scan_p2_kernel<<<1, 128, 0, stream>>>(bsum, bbase);
    scan_p3_kernel<<<SCAN_NB, 1024, 0, stream>>>(deg, bbase, start);
    scatter_kernel<<<(N_EDGES + 255) / 256, 256, 0, stream>>>(ei, start, cur, ssrc);

    // --- Layer 1 ---
    transform4_kernel<<<3125, 256, 0, stream>>>(x, Wk1, Wq1, Wv1, Ws1, b1,
                                                K, Qh, Vh, AGG);
    agg_kernel<<<N_NODES / 4, 256, 0, stream>>>(K, Qh, Vh, start, deg, ssrc, AGG);
    relu_gemm_kernel<<<1563, 256, 0, stream>>>(AGG, Wl1, bl1, H);

    // --- Layer 2 ---
    transform4_kernel<<<3125, 256, 0, stream>>>(H, Wk2, Wq2, Wv2, Ws2, b2,
                                                K, Qh, Vh, AGG);
    agg_kernel<<<N_NODES / 4, 256, 0, stream>>>(K, Qh, Vh, start, deg, ssrc, AGG);
    relu_gemm_kernel<<<1563, 256, 0, stream>>>(AGG, Wl2, bl2, (float*)d_out);
}

// Round 4
// 525.219 us; speedup vs baseline: 5.8304x; 1.1486x over previous
//
#include <hip/hip_runtime.h>

#define N_NODES 100000
#define N_EDGES 1600000
#define NB      782          // buckets of 128 dst nodes: 782*128 = 100096
#define NSB     (NB * 8)     // XCD-sharded sub-buckets
#define SBCAP   512          // per-sub-bucket capacity (mean ~256, 16 sigma)

typedef unsigned short ushort_t;
typedef unsigned int uint_t;

static __device__ __forceinline__ ushort_t bf16_rne(float f) {
    uint_t u = __float_as_uint(f);
    u = (u + 0x7FFFu + ((u >> 16) & 1u)) >> 16;
    return (ushort_t)u;
}
static __device__ __forceinline__ uint_t bfpack(float lo, float hi) {
    return (uint_t)bf16_rne(lo) | ((uint_t)bf16_rne(hi) << 16);
}
static __device__ __forceinline__ float bf2f(ushort_t h) {
    return __uint_as_float(((uint_t)h) << 16);
}

// Accumulate 16 outputs from one x value and four float4 weight chunks.
#define FMA16(A, xv) do { \
    A[0]  = fmaf((xv), wa.x, A[0]);  A[1]  = fmaf((xv), wa.y, A[1]);  \
    A[2]  = fmaf((xv), wa.z, A[2]);  A[3]  = fmaf((xv), wa.w, A[3]);  \
    A[4]  = fmaf((xv), wb.x, A[4]);  A[5]  = fmaf((xv), wb.y, A[5]);  \
    A[6]  = fmaf((xv), wb.z, A[6]);  A[7]  = fmaf((xv), wb.w, A[7]);  \
    A[8]  = fmaf((xv), wc.x, A[8]);  A[9]  = fmaf((xv), wc.y, A[9]);  \
    A[10] = fmaf((xv), wc.z, A[10]); A[11] = fmaf((xv), wc.w, A[11]); \
    A[12] = fmaf((xv), wd.x, A[12]); A[13] = fmaf((xv), wd.y, A[13]); \
    A[14] = fmaf((xv), wd.z, A[14]); A[15] = fmaf((xv), wd.w, A[15]); \
} while (0)

// ---------------------------------------------------------------------------
// CSR build pass A: scatter edges into 128-node buckets, XCD-sharded 8 ways.
// Active write-front set = NSB cache lines (~400KB) -> L2-resident, lines fill
// completely before eviction (vs 100K fronts previously = 16x amplification).
// ---------------------------------------------------------------------------
__global__ __launch_bounds__(256) void bucket_kernel(
    const int* __restrict__ EI, int* __restrict__ bcnt, uint_t* __restrict__ bbuf)
{
    int e = blockIdx.x * 256 + threadIdx.x;
    if (e >= N_EDGES) return;
    int s = EI[e];
    int d = EI[N_EDGES + e];
    int sb = (d >> 7) * 8 + (blockIdx.x & 7);
    int p = atomicAdd(&bcnt[sb], 1);
    if (p < SBCAP)  // statistically impossible overflow; guard memory only
        bbuf[(size_t)sb * SBCAP + p] = (uint_t)s | ((uint_t)(d & 127) << 17);
}

// Pass A2: exclusive scan of the 782 bucket totals (single block).
__global__ __launch_bounds__(1024) void bucket_scan_kernel(
    const int* __restrict__ bcnt, int* __restrict__ bbase)
{
    __shared__ int s[1024];
    int tid = threadIdx.x;
    int tot = 0;
    if (tid < NB) {
        #pragma unroll
        for (int j = 0; j < 8; ++j) {
            int c = bcnt[tid * 8 + j];
            tot += (c < SBCAP) ? c : SBCAP;
        }
    }
    s[tid] = tot;
    __syncthreads();
    for (int off = 1; off < 1024; off <<= 1) {
        int t = (tid >= off) ? s[tid - off] : 0;
        __syncthreads();
        s[tid] += t;
        __syncthreads();
    }
    if (tid < NB) bbase[tid] = s[tid] - tot;
}

// Pass B: one block per bucket. LDS histogram + scan of the 128 local dsts,
// coalesced deg/start writes (no global atomics), then scatter ssrc into the
// bucket's contiguous ~8KB window straight from LDS.
__global__ __launch_bounds__(256) void csr_kernel(
    const int* __restrict__ bcnt, const uint_t* __restrict__ bbuf,
    const int* __restrict__ bbase,
    int* __restrict__ deg, int* __restrict__ start, int* __restrict__ ssrc)
{
    __shared__ uint_t ebuf[8 * SBCAP];
    __shared__ int cnt[128];
    __shared__ int lst[128];
    __shared__ int scnt[8];
    __shared__ int soff[8];
    const int b = blockIdx.x, tid = threadIdx.x;

    if (tid < 8) {
        int c = bcnt[b * 8 + tid];
        scnt[tid] = (c < SBCAP) ? c : SBCAP;
    }
    if (tid < 128) cnt[tid] = 0;
    __syncthreads();
    if (tid == 0) {
        int r = 0;
        #pragma unroll
        for (int j = 0; j < 8; ++j) { soff[j] = r; r += scnt[j]; }
    }
    __syncthreads();
    const int total = soff[7] + scnt[7];

    for (int j = 0; j < 8; ++j) {
        int c = scnt[j], o = soff[j];
        const uint_t* src = bbuf + (size_t)(b * 8 + j) * SBCAP;
        for (int i = tid; i < c; i += 256) {
            uint_t u = src[i];
            ebuf[o + i] = u;
            atomicAdd(&cnt[(u >> 17) & 127], 1);
        }
    }
    __syncthreads();

    // inclusive scan of cnt -> lst
    if (tid < 128) lst[tid] = cnt[tid];
    __syncthreads();
    for (int off = 1; off < 128; off <<= 1) {
        int t = (tid < 128 && tid >= off) ? lst[tid - off] : 0;
        __syncthreads();
        if (tid < 128) lst[tid] += t;
        __syncthreads();
    }
    const int base = bbase[b];
    if (tid < 128) {
        lst[tid] -= cnt[tid];              // exclusive
        int n = b * 128 + tid;             // max 100095 < 100352 (array size)
        deg[n] = cnt[tid];
        start[n] = base + lst[tid];
        cnt[tid] = 0;                      // reuse as cursor
    }
    __syncthreads();

    for (int i = tid; i < total; i += 256) {
        uint_t u = ebuf[i];
        int dl = (u >> 17) & 127;
        int pos = base + lst[dl] + atomicAdd(&cnt[dl], 1);
        ssrc[pos] = (int)(u & 0x1FFFFu);
    }
}

// ---------------------------------------------------------------------------
// Kernel A: 4 simultaneous node transforms of X (fp32, 64 cols).
//   mat 0 -> K (fp32), mat 1 -> Qh (bf16), mat 2 -> Vh (bf16),
//   mat 3 -> AGG (fp32, + bias B3)  [skip-connection init]
// ---------------------------------------------------------------------------
__global__ __launch_bounds__(256) void transform4_kernel(
    const float* __restrict__ X,
    const float* __restrict__ W0, const float* __restrict__ W1,
    const float* __restrict__ W2, const float* __restrict__ W3,
    const float* __restrict__ B3,
    float* __restrict__ K, ushort_t* __restrict__ Qh,
    ushort_t* __restrict__ Vh, float* __restrict__ AGG)
{
    __shared__ float xs[32][65];
    __shared__ float ws[4][64][64];
    const int tid  = threadIdx.x;
    const int base = blockIdx.x * 32;

    {
        float4* d0 = (float4*)&ws[0][0][0];
        float4* d1 = (float4*)&ws[1][0][0];
        float4* d2 = (float4*)&ws[2][0][0];
        float4* d3 = (float4*)&ws[3][0][0];
        for (int i = tid; i < 1024; i += 256) {
            d0[i] = ((const float4*)W0)[i];
            d1[i] = ((const float4*)W1)[i];
            d2[i] = ((const float4*)W2)[i];
            d3[i] = ((const float4*)W3)[i];
        }
    }
    for (int i = tid; i < 512; i += 256) {
        int r = i >> 4, c = i & 15;
        int node = base + r;                 // 3125*32 == 100000, in range
        float4 v = ((const float4*)X)[node * 16 + c];
        *(float4*)&xs[r][c * 4] = v;
    }
    __syncthreads();

    const int mat  = tid >> 6;      // wave-uniform
    const int lane = tid & 63;
    const int ng   = lane >> 2;     // rows 2ng, 2ng+1
    const int og   = (lane & 3) * 16;

    float acc0[16], acc1[16];
    #pragma unroll
    for (int j = 0; j < 16; ++j) { acc0[j] = 0.f; acc1[j] = 0.f; }

    for (int k = 0; k < 64; ++k) {
        float4 wa = *(const float4*)&ws[mat][k][og + 0];
        float4 wb = *(const float4*)&ws[mat][k][og + 4];
        float4 wc = *(const float4*)&ws[mat][k][og + 8];
        float4 wd = *(const float4*)&ws[mat][k][og + 12];
        float x0 = xs[2 * ng + 0][k];
        float x1 = xs[2 * ng + 1][k];
        FMA16(acc0, x0);
        FMA16(acc1, x1);
    }

    if (mat == 0 || mat == 3) {
        float bias[16];
        #pragma unroll
        for (int j = 0; j < 16; ++j) bias[j] = (mat == 3) ? B3[og + j] : 0.f;
        float* O = (mat == 0) ? K : AGG;
        #pragma unroll
        for (int i = 0; i < 2; ++i) {
            int node = base + 2 * ng + i;
            float* dst = O + (size_t)node * 64 + og;
            const float* A = (i == 0) ? acc0 : acc1;
            *(float4*)(dst + 0)  = make_float4(A[0]  + bias[0],  A[1]  + bias[1],
                                               A[2]  + bias[2],  A[3]  + bias[3]);
            *(float4*)(dst + 4)  = make_float4(A[4]  + bias[4],  A[5]  + bias[5],
                                               A[6]  + bias[6],  A[7]  + bias[7]);
            *(float4*)(dst + 8)  = make_float4(A[8]  + bias[8],  A[9]  + bias[9],
                                               A[10] + bias[10], A[11] + bias[11]);
            *(float4*)(dst + 12) = make_float4(A[12] + bias[12], A[13] + bias[13],
                                               A[14] + bias[14], A[15] + bias[15]);
        }
    } else {
        ushort_t* O = (mat == 1) ? Qh : Vh;
        #pragma unroll
        for (int i = 0; i < 2; ++i) {
            int node = base + 2 * ng + i;
            uint_t* dst = (uint_t*)(O + (size_t)node * 64 + og);
            const float* A = (i == 0) ? acc0 : acc1;
            uint4 u0, u1;
            u0.x = bfpack(A[0],  A[1]);  u0.y = bfpack(A[2],  A[3]);
            u0.z = bfpack(A[4],  A[5]);  u0.w = bfpack(A[6],  A[7]);
            u1.x = bfpack(A[8],  A[9]);  u1.y = bfpack(A[10], A[11]);
            u1.z = bfpack(A[12], A[13]); u1.w = bfpack(A[14], A[15]);
            *(uint4*)(dst + 0) = u0;
            *(uint4*)(dst + 4) = u1;
        }
    }
}

// ---------------------------------------------------------------------------
// Kernel B: atomic-free aggregation, bf16 gathers. One wave per node.
// ---------------------------------------------------------------------------
__global__ __launch_bounds__(256) void agg_kernel(
    const float* __restrict__ K, const ushort_t* __restrict__ Qh,
    const ushort_t* __restrict__ Vh, const int* __restrict__ start,
    const int* __restrict__ deg, const int* __restrict__ ssrc,
    float* __restrict__ AGG)
{
    int n = (blockIdx.x * 256 + threadIdx.x) >> 6;   // grid sized exactly
    int lane = threadIdx.x & 63;
    int eg = lane >> 4;            // edge slot 0..3
    int c  = (lane & 15) * 4;      // column group

    const float4 kv = *(const float4*)(K + (size_t)n * 64 + c);
    float4 acc = make_float4(0.f, 0.f, 0.f, 0.f);

    int s0 = start[n];
    int dn = deg[n];
    for (int p = eg; p < dn; p += 4) {
        int s = ssrc[s0 + p];
        ushort4 qh = *(const ushort4*)(Qh + (size_t)s * 64 + c);
        ushort4 vh = *(const ushort4*)(Vh + (size_t)s * 64 + c);
        acc.x += bf2f(vh.x) / (1.f + __expf(-(kv.x + bf2f(qh.x))));
        acc.y += bf2f(vh.y) / (1.f + __expf(-(kv.y + bf2f(qh.y))));
        acc.z += bf2f(vh.z) / (1.f + __expf(-(kv.z + bf2f(qh.z))));
        acc.w += bf2f(vh.w) / (1.f + __expf(-(kv.w + bf2f(qh.w))));
    }

    acc.x += __shfl_xor(acc.x, 16); acc.y += __shfl_xor(acc.y, 16);
    acc.z += __shfl_xor(acc.z, 16); acc.w += __shfl_xor(acc.w, 16);
    acc.x += __shfl_xor(acc.x, 32); acc.y += __shfl_xor(acc.y, 32);
    acc.z += __shfl_xor(acc.z, 32); acc.w += __shfl_xor(acc.w, 32);

    if (eg == 0) {
        float4* a = (float4*)(AGG + (size_t)n * 64 + c);
        float4 o = *a;
        o.x += acc.x; o.y += acc.y; o.z += acc.z; o.w += acc.w;
        *a = o;
    }
}

// ---------------------------------------------------------------------------
// Kernel C: out = relu(agg @ Wl + bl).  33KB LDS -> 4 blocks/CU.
// ---------------------------------------------------------------------------
__global__ __launch_bounds__(256) void relu_gemm_kernel(
    const float* __restrict__ AGG, const float* __restrict__ WL,
    const float* __restrict__ BL, float* __restrict__ OUT)
{
    __shared__ float xin[64][65];
    __shared__ float wl[64][64];
    const int tid  = threadIdx.x;
    const int base = blockIdx.x * 64;

    {
        float4* dl = (float4*)&wl[0][0];
        for (int i = tid; i < 1024; i += 256) dl[i] = ((const float4*)WL)[i];
    }
    for (int i = tid; i < 1024; i += 256) {
        int r = i >> 4, c = i & 15;
        int node = base + r;
        float4 v = make_float4(0.f, 0.f, 0.f, 0.f);
        if (node < N_NODES) v = ((const float4*)AGG)[node * 16 + c];
        *(float4*)&xin[r][c * 4] = v;
    }
    __syncthreads();

    const int node = tid >> 2;
    const int og   = (tid & 3) * 16;
    float acc[16];
    #pragma unroll
    for (int j = 0; j < 16; ++j) acc[j] = 0.f;
    for (int k = 0; k < 64; ++k) {
        float4 wa = *(const float4*)&wl[k][og + 0];
        float4 wb = *(const float4*)&wl[k][og + 4];
        float4 wc = *(const float4*)&wl[k][og + 8];
        float4 wd = *(const float4*)&wl[k][og + 12];
        float xv = xin[node][k];
        FMA16(acc, xv);
    }

    int out_node = base + node;
    if (out_node < N_NODES) {
        float* dst = OUT + (size_t)out_node * 64 + og;
        float r0[16];
        #pragma unroll
        for (int j = 0; j < 16; ++j) r0[j] = fmaxf(acc[j] + BL[og + j], 0.f);
        *(float4*)(dst + 0)  = make_float4(r0[0],  r0[1],  r0[2],  r0[3]);
        *(float4*)(dst + 4)  = make_float4(r0[4],  r0[5],  r0[6],  r0[7]);
        *(float4*)(dst + 8)  = make_float4(r0[8],  r0[9],  r0[10], r0[11]);
        *(float4*)(dst + 12) = make_float4(r0[12], r0[13], r0[14], r0[15]);
    }
}

extern "C" void kernel_launch(void* const* d_in, const int* in_sizes, int n_in,
                              void* d_out, int out_size, void* d_ws, size_t ws_size,
                              hipStream_t stream)
{
    const float* x   = (const float*)d_in[0];
    const float* Wk1 = (const float*)d_in[1];
    const float* Wq1 = (const float*)d_in[2];
    const float* Wv1 = (const float*)d_in[3];
    const float* Ws1 = (const float*)d_in[4];
    const float* b1  = (const float*)d_in[5];
    const float* Wl1 = (const float*)d_in[6];
    const float* bl1 = (const float*)d_in[7];
    const float* Wk2 = (const float*)d_in[8];
    const float* Wq2 = (const float*)d_in[9];
    const float* Wv2 = (const float*)d_in[10];
    const float* Ws2 = (const float*)d_in[11];
    const float* b2  = (const float*)d_in[12];
    const float* Wl2 = (const float*)d_in[13];
    const float* bl2 = (const float*)d_in[14];
    const int*   ei  = (const int*)d_in[15];

    const size_t NF = (size_t)N_NODES * 64;
    float*    K    = (float*)d_ws;
    float*    AGG  = K + NF;
    float*    H    = AGG + NF;
    ushort_t* Qh   = (ushort_t*)(H + NF);
    ushort_t* Vh   = Qh + NF;
    int*      bcnt = (int*)(Vh + NF);
    int*      bbase = bcnt + NSB;           // NSB = 6256, %4 == 0
    int*      deg   = bbase + 1024;
    int*      start = deg + 100352;
    int*      ssrc  = start + 100352;
    uint_t*   bbuf  = (uint_t*)(ssrc + N_EDGES);

    // --- CSR build ---
    hipMemsetAsync(bcnt, 0, NSB * sizeof(int), stream);
    bucket_kernel<<<N_EDGES / 256, 256, 0, stream>>>(ei, bcnt, bbuf);
    bucket_scan_kernel<<<1, 1024, 0, stream>>>(bcnt, bbase);
    csr_kernel<<<NB, 256, 0, stream>>>(bcnt, bbuf, bbase, deg, start, ssrc);

    // --- Layer 1 ---
    transform4_kernel<<<3125, 256, 0, stream>>>(x, Wk1, Wq1, Wv1, Ws1, b1,
                                                K, Qh, Vh, AGG);
    agg_kernel<<<N_NODES / 4, 256, 0, stream>>>(K, Qh, Vh, start, deg, ssrc, AGG);
    relu_gemm_kernel<<<1563, 256, 0, stream>>>(AGG, Wl1, bl1, H);

    // --- Layer 2 ---
    transform4_kernel<<<3125, 256, 0, stream>>>(H, Wk2, Wq2, Wv2, Ws2, b2,
                                                K, Qh, Vh, AGG);
    agg_kernel<<<N_NODES / 4, 256, 0, stream>>>(K, Qh, Vh, start, deg, ssrc, AGG);
    relu_gemm_kernel<<<1563, 256, 0, stream>>>(AGG, Wl2, bl2, (float*)d_out);
}

// Round 6
// 511.040 us; speedup vs baseline: 5.9922x; 1.0277x over previous
//
#include <hip/hip_runtime.h>

#define N_NODES 100000
#define N_EDGES 1600000
#define NB      782          // buckets of 128 dst nodes: 782*128 = 100096
#define NSB     (NB * 8)     // XCD-sharded sub-buckets
#define SBCAP   512          // per-sub-bucket capacity (mean ~256, 16 sigma)

typedef unsigned short ushort_t;
typedef unsigned int uint_t;

static __device__ __forceinline__ ushort_t bf16_rne(float f) {
    uint_t u = __float_as_uint(f);
    u = (u + 0x7FFFu + ((u >> 16) & 1u)) >> 16;
    return (ushort_t)u;
}
static __device__ __forceinline__ uint_t bfpack(float lo, float hi) {
    return (uint_t)bf16_rne(lo) | ((uint_t)bf16_rne(hi) << 16);
}
static __device__ __forceinline__ float bf2f(ushort_t h) {
    return __uint_as_float(((uint_t)h) << 16);
}

// Accumulate 16 outputs from one x value and four float4 weight chunks.
#define FMA16(A, xv) do { \
    A[0]  = fmaf((xv), wa.x, A[0]);  A[1]  = fmaf((xv), wa.y, A[1]);  \
    A[2]  = fmaf((xv), wa.z, A[2]);  A[3]  = fmaf((xv), wa.w, A[3]);  \
    A[4]  = fmaf((xv), wb.x, A[4]);  A[5]  = fmaf((xv), wb.y, A[5]);  \
    A[6]  = fmaf((xv), wb.z, A[6]);  A[7]  = fmaf((xv), wb.w, A[7]);  \
    A[8]  = fmaf((xv), wc.x, A[8]);  A[9]  = fmaf((xv), wc.y, A[9]);  \
    A[10] = fmaf((xv), wc.z, A[10]); A[11] = fmaf((xv), wc.w, A[11]); \
    A[12] = fmaf((xv), wd.x, A[12]); A[13] = fmaf((xv), wd.y, A[13]); \
    A[14] = fmaf((xv), wd.z, A[14]); A[15] = fmaf((xv), wd.w, A[15]); \
} while (0)

// ---------------------------------------------------------------------------
// CSR build pass A: scatter edges into 128-node buckets, XCD-sharded 8 ways.
// ---------------------------------------------------------------------------
__global__ __launch_bounds__(256) void bucket_kernel(
    const int* __restrict__ EI, int* __restrict__ bcnt, uint_t* __restrict__ bbuf)
{
    int e = blockIdx.x * 256 + threadIdx.x;
    if (e >= N_EDGES) return;
    int s = EI[e];
    int d = EI[N_EDGES + e];
    int sb = (d >> 7) * 8 + (blockIdx.x & 7);
    int p = atomicAdd(&bcnt[sb], 1);
    if (p < SBCAP)  // statistically impossible overflow; guard memory only
        bbuf[(size_t)sb * SBCAP + p] = (uint_t)s | ((uint_t)(d & 127) << 17);
}

// Pass A2: exclusive scan of the 782 bucket totals (single block).
__global__ __launch_bounds__(1024) void bucket_scan_kernel(
    const int* __restrict__ bcnt, int* __restrict__ bbase)
{
    __shared__ int s[1024];
    int tid = threadIdx.x;
    int tot = 0;
    if (tid < NB) {
        #pragma unroll
        for (int j = 0; j < 8; ++j) {
            int c = bcnt[tid * 8 + j];
            tot += (c < SBCAP) ? c : SBCAP;
        }
    }
    s[tid] = tot;
    __syncthreads();
    for (int off = 1; off < 1024; off <<= 1) {
        int t = (tid >= off) ? s[tid - off] : 0;
        __syncthreads();
        s[tid] += t;
        __syncthreads();
    }
    if (tid < NB) bbase[tid] = s[tid] - tot;
}

// Pass B: one block per bucket. LDS histogram + scan of 128 local dsts,
// coalesced deg/start writes, scatter ssrc into contiguous window from LDS.
__global__ __launch_bounds__(256) void csr_kernel(
    const int* __restrict__ bcnt, const uint_t* __restrict__ bbuf,
    const int* __restrict__ bbase,
    int* __restrict__ deg, int* __restrict__ start, int* __restrict__ ssrc)
{
    __shared__ uint_t ebuf[8 * SBCAP];
    __shared__ int cnt[128];
    __shared__ int lst[128];
    __shared__ int scnt[8];
    __shared__ int soff[8];
    const int b = blockIdx.x, tid = threadIdx.x;

    if (tid < 8) {
        int c = bcnt[b * 8 + tid];
        scnt[tid] = (c < SBCAP) ? c : SBCAP;
    }
    if (tid < 128) cnt[tid] = 0;
    __syncthreads();
    if (tid == 0) {
        int r = 0;
        #pragma unroll
        for (int j = 0; j < 8; ++j) { soff[j] = r; r += scnt[j]; }
    }
    __syncthreads();
    const int total = soff[7] + scnt[7];

    for (int j = 0; j < 8; ++j) {
        int c = scnt[j], o = soff[j];
        const uint_t* src = bbuf + (size_t)(b * 8 + j) * SBCAP;
        for (int i = tid; i < c; i += 256) {
            uint_t u = src[i];
            ebuf[o + i] = u;
            atomicAdd(&cnt[(u >> 17) & 127], 1);
        }
    }
    __syncthreads();

    if (tid < 128) lst[tid] = cnt[tid];
    __syncthreads();
    for (int off = 1; off < 128; off <<= 1) {
        int t = (tid < 128 && tid >= off) ? lst[tid - off] : 0;
        __syncthreads();
        if (tid < 128) lst[tid] += t;
        __syncthreads();
    }
    const int base = bbase[b];
    if (tid < 128) {
        lst[tid] -= cnt[tid];              // exclusive
        int n = b * 128 + tid;
        deg[n] = cnt[tid];
        start[n] = base + lst[tid];
        cnt[tid] = 0;                      // reuse as cursor
    }
    __syncthreads();

    for (int i = tid; i < total; i += 256) {
        uint_t u = ebuf[i];
        int dl = (u >> 17) & 127;
        int pos = base + lst[dl] + atomicAdd(&cnt[dl], 1);
        ssrc[pos] = (int)(u & 0x1FFFFu);
    }
}

// ---------------------------------------------------------------------------
// Kernel A: node transforms, 64-node x 2-matrix blocks (gridDim.y selects
// the pair). LDS = 16.3K xs + 32K ws = 48.3KB -> 3 blocks/CU (was 2).
//   y=0: mat0 -> K (fp32),  mat1 -> Qh (bf16)
//   y=1: mat0 -> Vh (bf16), mat1 -> AGG (fp32 + bias B3)
// ---------------------------------------------------------------------------
__global__ __launch_bounds__(256) void transform4_kernel(
    const float* __restrict__ X,
    const float* __restrict__ W0, const float* __restrict__ W1,
    const float* __restrict__ W2, const float* __restrict__ W3,
    const float* __restrict__ B3,
    float* __restrict__ K, ushort_t* __restrict__ Qh,
    ushort_t* __restrict__ Vh, float* __restrict__ AGG)
{
    __shared__ float xs[64][65];
    __shared__ float ws[2][64][64];
    const int tid  = threadIdx.x;
    const int base = blockIdx.x * 64;
    const int pair = blockIdx.y;

    {
        const float* WA = pair ? W2 : W0;
        const float* WB = pair ? W3 : W1;
        float4* dA = (float4*)&ws[0][0][0];
        float4* dB = (float4*)&ws[1][0][0];
        for (int i = tid; i < 1024; i += 256) {
            dA[i] = ((const float4*)WA)[i];
            dB[i] = ((const float4*)WB)[i];
        }
    }
    for (int i = tid; i < 1024; i += 256) {
        int r = i >> 4, c = i & 15;
        int node = base + r;
        float4 v = make_float4(0.f, 0.f, 0.f, 0.f);
        if (node < N_NODES) v = ((const float4*)X)[(size_t)node * 16 + c];
        *(float4*)&xs[r][c * 4] = v;
    }
    __syncthreads();

    const int wid    = tid >> 6;
    const int lane   = tid & 63;
    const int matsel = wid >> 1;                 // wave-uniform: 0 -> WA, 1 -> WB
    const int lg     = ((wid & 1) << 6) | lane;  // 0..127 within matrix
    const int ng     = lg >> 2;                  // 0..31 -> rows 2ng, 2ng+1
    const int og     = (lg & 3) * 16;

    float acc0[16], acc1[16];
    #pragma unroll
    for (int j = 0; j < 16; ++j) { acc0[j] = 0.f; acc1[j] = 0.f; }

    for (int k = 0; k < 64; ++k) {
        float4 wa = *(const float4*)&ws[matsel][k][og + 0];
        float4 wb = *(const float4*)&ws[matsel][k][og + 4];
        float4 wc = *(const float4*)&ws[matsel][k][og + 8];
        float4 wd = *(const float4*)&ws[matsel][k][og + 12];
        float x0 = xs[2 * ng + 0][k];
        float x1 = xs[2 * ng + 1][k];
        FMA16(acc0, x0);
        FMA16(acc1, x1);
    }

    const int kind = pair * 2 + matsel;   // 0:K 1:Qh 2:Vh 3:AGG
    if (kind == 0 || kind == 3) {
        float bias[16];
        #pragma unroll
        for (int j = 0; j < 16; ++j) bias[j] = (kind == 3) ? B3[og + j] : 0.f;
        float* O = (kind == 0) ? K : AGG;
        #pragma unroll
        for (int i = 0; i < 2; ++i) {
            int node = base + 2 * ng + i;
            if (node < N_NODES) {
                float* dst = O + (size_t)node * 64 + og;
                const float* A = (i == 0) ? acc0 : acc1;
                *(float4*)(dst + 0)  = make_float4(A[0]  + bias[0],  A[1]  + bias[1],
                                                   A[2]  + bias[2],  A[3]  + bias[3]);
                *(float4*)(dst + 4)  = make_float4(A[4]  + bias[4],  A[5]  + bias[5],
                                                   A[6]  + bias[6],  A[7]  + bias[7]);
                *(float4*)(dst + 8)  = make_float4(A[8]  + bias[8],  A[9]  + bias[9],
                                                   A[10] + bias[10], A[11] + bias[11]);
                *(float4*)(dst + 12) = make_float4(A[12] + bias[12], A[13] + bias[13],
                                                   A[14] + bias[14], A[15] + bias[15]);
            }
        }
    } else {
        ushort_t* O = (kind == 1) ? Qh : Vh;
        #pragma unroll
        for (int i = 0; i < 2; ++i) {
            int node = base + 2 * ng + i;
            if (node < N_NODES) {
                uint_t* dst = (uint_t*)(O + (size_t)node * 64 + og);
                const float* A = (i == 0) ? acc0 : acc1;
                uint4 u0, u1;
                u0.x = bfpack(A[0],  A[1]);  u0.y = bfpack(A[2],  A[3]);
                u0.z = bfpack(A[4],  A[5]);  u0.w = bfpack(A[6],  A[7]);
                u1.x = bfpack(A[8],  A[9]);  u1.y = bfpack(A[10], A[11]);
                u1.z = bfpack(A[12], A[13]); u1.w = bfpack(A[14], A[15]);
                *(uint4*)(dst + 0) = u0;
                *(uint4*)(dst + 4) = u1;
            }
        }
    }
}

// ---------------------------------------------------------------------------
// Kernel B: atomic-free aggregation, bf16 gathers, fast sigmoid (v_rcp).
// One wave per node; 4 edge slots x 16 column lanes.
// ---------------------------------------------------------------------------
__global__ __launch_bounds__(256) void agg_kernel(
    const float* __restrict__ K, const ushort_t* __restrict__ Qh,
    const ushort_t* __restrict__ Vh, const int* __restrict__ start,
    const int* __restrict__ deg, const int* __restrict__ ssrc,
    float* __restrict__ AGG)
{
    int n = (blockIdx.x * 256 + threadIdx.x) >> 6;   // grid sized exactly
    int lane = threadIdx.x & 63;
    int eg = lane >> 4;            // edge slot 0..3
    int c  = (lane & 15) * 4;      // column group

    const float4 kv = *(const float4*)(K + (size_t)n * 64 + c);
    float4 acc = make_float4(0.f, 0.f, 0.f, 0.f);

    int s0 = start[n];
    int dn = deg[n];
    for (int p = eg; p < dn; p += 4) {
        int s = ssrc[s0 + p];
        ushort4 qh = *(const ushort4*)(Qh + (size_t)s * 64 + c);
        ushort4 vh = *(const ushort4*)(Vh + (size_t)s * 64 + c);
        float ex = __expf(-(kv.x + bf2f(qh.x)));
        float ey = __expf(-(kv.y + bf2f(qh.y)));
        float ez = __expf(-(kv.z + bf2f(qh.z)));
        float ew = __expf(-(kv.w + bf2f(qh.w)));
        acc.x = fmaf(bf2f(vh.x), __builtin_amdgcn_rcpf(1.f + ex), acc.x);
        acc.y = fmaf(bf2f(vh.y), __builtin_amdgcn_rcpf(1.f + ey), acc.y);
        acc.z = fmaf(bf2f(vh.z), __builtin_amdgcn_rcpf(1.f + ez), acc.z);
        acc.w = fmaf(bf2f(vh.w), __builtin_amdgcn_rcpf(1.f + ew), acc.w);
    }

    acc.x += __shfl_xor(acc.x, 16); acc.y += __shfl_xor(acc.y, 16);
    acc.z += __shfl_xor(acc.z, 16); acc.w += __shfl_xor(acc.w, 16);
    acc.x += __shfl_xor(acc.x, 32); acc.y += __shfl_xor(acc.y, 32);
    acc.z += __shfl_xor(acc.z, 32); acc.w += __shfl_xor(acc.w, 32);

    if (eg == 0) {
        float4* a = (float4*)(AGG + (size_t)n * 64 + c);
        float4 o = *a;
        o.x += acc.x; o.y += acc.y; o.z += acc.z; o.w += acc.w;
        *a = o;
    }
}

// ---------------------------------------------------------------------------
// Kernel C: out = relu(agg @ Wl + bl).  33KB LDS -> 4 blocks/CU.
// ---------------------------------------------------------------------------
__global__ __launch_bounds__(256) void relu_gemm_kernel(
    const float* __restrict__ AGG, const float* __restrict__ WL,
    const float* __restrict__ BL, float* __restrict__ OUT)
{
    __shared__ float xin[64][65];
    __shared__ float wl[64][64];
    const int tid  = threadIdx.x;
    const int base = blockIdx.x * 64;

    {
        float4* dl = (float4*)&wl[0][0];
        for (int i = tid; i < 1024; i += 256) dl[i] = ((const float4*)WL)[i];
    }
    for (int i = tid; i < 1024; i += 256) {
        int r = i >> 4, c = i & 15;
        int node = base + r;
        float4 v = make_float4(0.f, 0.f, 0.f, 0.f);
        if (node < N_NODES) v = ((const float4*)AGG)[(size_t)node * 16 + c];
        *(float4*)&xin[r][c * 4] = v;
    }
    __syncthreads();

    const int node = tid >> 2;
    const int og   = (tid & 3) * 16;
    float acc[16];
    #pragma unroll
    for (int j = 0; j < 16; ++j) acc[j] = 0.f;
    for (int k = 0; k < 64; ++k) {
        float4 wa = *(const float4*)&wl[k][og + 0];
        float4 wb = *(const float4*)&wl[k][og + 4];
        float4 wc = *(const float4*)&wl[k][og + 8];
        float4 wd = *(const float4*)&wl[k][og + 12];
        float xv = xin[node][k];
        FMA16(acc, xv);
    }

    int out_node = base + node;
    if (out_node < N_NODES) {
        float* dst = OUT + (size_t)out_node * 64 + og;
        float r0[16];
        #pragma unroll
        for (int j = 0; j < 16; ++j) r0[j] = fmaxf(acc[j] + BL[og + j], 0.f);
        *(float4*)(dst + 0)  = make_float4(r0[0],  r0[1],  r0[2],  r0[3]);
        *(float4*)(dst + 4)  = make_float4(r0[4],  r0[5],  r0[6],  r0[7]);
        *(float4*)(dst + 8)  = make_float4(r0[8],  r0[9],  r0[10], r0[11]);
        *(float4*)(dst + 12) = make_float4(r0[12], r0[13], r0[14], r0[15]);
    }
}

extern "C" void kernel_launch(void* const* d_in, const int* in_sizes, int n_in,
                              void* d_out, int out_size, void* d_ws, size_t ws_size,
                              hipStream_t stream)
{
    const float* x   = (const float*)d_in[0];
    const float* Wk1 = (const float*)d_in[1];
    const float* Wq1 = (const float*)d_in[2];
    const float* Wv1 = (const float*)d_in[3];
    const float* Ws1 = (const float*)d_in[4];
    const float* b1  = (const float*)d_in[5];
    const float* Wl1 = (const float*)d_in[6];
    const float* bl1 = (const float*)d_in[7];
    const float* Wk2 = (const float*)d_in[8];
    const float* Wq2 = (const float*)d_in[9];
    const float* Wv2 = (const float*)d_in[10];
    const float* Ws2 = (const float*)d_in[11];
    const float* b2  = (const float*)d_in[12];
    const float* Wl2 = (const float*)d_in[13];
    const float* bl2 = (const float*)d_in[14];
    const int*   ei  = (const int*)d_in[15];

    const size_t NF = (size_t)N_NODES * 64;
    float*    K    = (float*)d_ws;
    float*    AGG  = K + NF;
    float*    H    = AGG + NF;
    ushort_t* Qh   = (ushort_t*)(H + NF);
    ushort_t* Vh   = Qh + NF;
    int*      bcnt = (int*)(Vh + NF);
    int*      bbase = bcnt + NSB;
    int*      deg   = bbase + 1024;
    int*      start = deg + 100352;
    int*      ssrc  = start + 100352;
    uint_t*   bbuf  = (uint_t*)(ssrc + N_EDGES);

    // --- CSR build ---
    hipMemsetAsync(bcnt, 0, NSB * sizeof(int), stream);
    bucket_kernel<<<N_EDGES / 256, 256, 0, stream>>>(ei, bcnt, bbuf);
    bucket_scan_kernel<<<1, 1024, 0, stream>>>(bcnt, bbase);
    csr_kernel<<<NB, 256, 0, stream>>>(bcnt, bbuf, bbase, deg, start, ssrc);

    // --- Layer 1 ---
    transform4_kernel<<<dim3(1563, 2), 256, 0, stream>>>(x, Wk1, Wq1, Wv1, Ws1, b1,
                                                         K, Qh, Vh, AGG);
    agg_kernel<<<N_NODES / 4, 256, 0, stream>>>(K, Qh, Vh, start, deg, ssrc, AGG);
    relu_gemm_kernel<<<1563, 256, 0, stream>>>(AGG, Wl1, bl1, H);

    // --- Layer 2 ---
    transform4_kernel<<<dim3(1563, 2), 256, 0, stream>>>(H, Wk2, Wq2, Wv2, Ws2, b2,
                                                         K, Qh, Vh, AGG);
    agg_kernel<<<N_NODES / 4, 256, 0, stream>>>(K, Qh, Vh, start, deg, ssrc, AGG);
    relu_gemm_kernel<<<1563, 256, 0, stream>>>(AGG, Wl2, bl2, (float*)d_out);
}

// Round 7
// 478.495 us; speedup vs baseline: 6.3997x; 1.0680x over previous
//
#include <hip/hip_runtime.h>

#define N_NODES 100000
#define N_EDGES 1600000
#define NB      782          // buckets of 128 dst nodes: 782*128 = 100096
#define NBLK_E  256          // edge-pass blocks
#define CHUNK_E 6250         // edges per block: 256*6250 = 1.6M exactly
#define EBUF_CAP 4096        // per-bucket LDS cap (mean 2048, sd ~45 -> 45 sigma)

typedef unsigned short ushort_t;
typedef unsigned int uint_t;

static __device__ __forceinline__ ushort_t bf16_rne(float f) {
    uint_t u = __float_as_uint(f);
    u = (u + 0x7FFFu + ((u >> 16) & 1u)) >> 16;
    return (ushort_t)u;
}
static __device__ __forceinline__ uint_t bfpack(float lo, float hi) {
    return (uint_t)bf16_rne(lo) | ((uint_t)bf16_rne(hi) << 16);
}
static __device__ __forceinline__ float bf2f(ushort_t h) {
    return __uint_as_float(((uint_t)h) << 16);
}

// Accumulate 16 outputs from one x value and four float4 weight chunks.
#define FMA16(A, xv) do { \
    A[0]  = fmaf((xv), wa.x, A[0]);  A[1]  = fmaf((xv), wa.y, A[1]);  \
    A[2]  = fmaf((xv), wa.z, A[2]);  A[3]  = fmaf((xv), wa.w, A[3]);  \
    A[4]  = fmaf((xv), wb.x, A[4]);  A[5]  = fmaf((xv), wb.y, A[5]);  \
    A[6]  = fmaf((xv), wb.z, A[6]);  A[7]  = fmaf((xv), wb.w, A[7]);  \
    A[8]  = fmaf((xv), wc.x, A[8]);  A[9]  = fmaf((xv), wc.y, A[9]);  \
    A[10] = fmaf((xv), wc.z, A[10]); A[11] = fmaf((xv), wc.w, A[11]); \
    A[12] = fmaf((xv), wd.x, A[12]); A[13] = fmaf((xv), wd.y, A[13]); \
    A[14] = fmaf((xv), wd.z, A[14]); A[15] = fmaf((xv), wd.w, A[15]); \
} while (0)

// ---------------------------------------------------------------------------
// CSR build pass A: per-block LDS histogram of dst buckets. NO global atomics.
// Writes one coalesced 782-int row per block (covers every entry -> no memset).
// ---------------------------------------------------------------------------
__global__ __launch_bounds__(256) void hist782_kernel(
    const int* __restrict__ EI, int* __restrict__ hmat)
{
    __shared__ int h[NB];
    const int tid = threadIdx.x;
    for (int i = tid; i < NB; i += 256) h[i] = 0;
    __syncthreads();
    const int e0 = blockIdx.x * CHUNK_E;
    for (int i = tid; i < CHUNK_E; i += 256) {
        int d = EI[N_EDGES + e0 + i];
        atomicAdd(&h[d >> 7], 1);
    }
    __syncthreads();
    int* row = hmat + blockIdx.x * NB;
    for (int i = tid; i < NB; i += 256) row[i] = h[i];
}

// Pass B: single block. Column-exclusive-scan of hmat[256][782] in place
// (row sweeps are coalesced across the 782 bucket-threads), then LDS scan of
// bucket totals -> bbase2 (bucket base) and btot (bucket size).
__global__ __launch_bounds__(1024) void colscan_kernel(
    int* __restrict__ hmat, int* __restrict__ bbase2, int* __restrict__ btot)
{
    __shared__ int s[1024];
    const int tid = threadIdx.x;
    int run = 0;
    if (tid < NB) {
        for (int blk = 0; blk < NBLK_E; ++blk) {
            int idx = blk * NB + tid;
            int v = hmat[idx];
            hmat[idx] = run;      // exclusive within-bucket prefix
            run += v;
        }
    }
    s[tid] = (tid < NB) ? run : 0;
    __syncthreads();
    for (int off = 1; off < 1024; off <<= 1) {
        int t = (tid >= off) ? s[tid - off] : 0;
        __syncthreads();
        s[tid] += t;
        __syncthreads();
    }
    if (tid < NB) {
        bbase2[tid] = s[tid] - run;   // exclusive across buckets
        btot[tid]   = run;
    }
}

// Pass C: deterministic scatter into bucket-contiguous sbuf. LDS cursors only.
__global__ __launch_bounds__(256) void scat782_kernel(
    const int* __restrict__ EI, const int* __restrict__ hmat,
    const int* __restrict__ bbase2, uint_t* __restrict__ sbuf)
{
    __shared__ int base[NB];
    __shared__ int cur[NB];
    const int tid = threadIdx.x;
    const int* row = hmat + blockIdx.x * NB;
    for (int i = tid; i < NB; i += 256) {
        base[i] = bbase2[i] + row[i];
        cur[i] = 0;
    }
    __syncthreads();
    const int e0 = blockIdx.x * CHUNK_E;
    for (int i = tid; i < CHUNK_E; i += 256) {
        int sN = EI[e0 + i];
        int d  = EI[N_EDGES + e0 + i];
        int b  = d >> 7;
        int p  = base[b] + atomicAdd(&cur[b], 1);
        sbuf[p] = (uint_t)sN | ((uint_t)(d & 127) << 17);
    }
}

// Pass D: one block per bucket (entries now contiguous & exactly counted).
// LDS histogram + scan of 128 local dsts, coalesced deg/start writes,
// dst-sorted scatter of ssrc within the bucket window.
__global__ __launch_bounds__(256) void csr_kernel(
    const int* __restrict__ bbase2, const int* __restrict__ btot,
    const uint_t* __restrict__ sbuf,
    int* __restrict__ deg, int* __restrict__ start, int* __restrict__ ssrc)
{
    __shared__ uint_t ebuf[EBUF_CAP];
    __shared__ int cnt[128];
    __shared__ int lst[128];
    const int b = blockIdx.x, tid = threadIdx.x;
    const int base = bbase2[b];
    int total = btot[b];
    if (total > EBUF_CAP) total = EBUF_CAP;   // 45-sigma safety clamp

    if (tid < 128) cnt[tid] = 0;
    __syncthreads();

    for (int i = tid; i < total; i += 256) {
        uint_t u = sbuf[base + i];
        ebuf[i] = u;
        atomicAdd(&cnt[(u >> 17) & 127], 1);
    }
    __syncthreads();

    if (tid < 128) lst[tid] = cnt[tid];
    __syncthreads();
    for (int off = 1; off < 128; off <<= 1) {
        int t = (tid < 128 && tid >= off) ? lst[tid - off] : 0;
        __syncthreads();
        if (tid < 128) lst[tid] += t;
        __syncthreads();
    }
    if (tid < 128) {
        lst[tid] -= cnt[tid];              // exclusive
        int n = b * 128 + tid;
        deg[n] = cnt[tid];
        start[n] = base + lst[tid];
        cnt[tid] = 0;                      // reuse as cursor
    }
    __syncthreads();

    for (int i = tid; i < total; i += 256) {
        uint_t u = ebuf[i];
        int dl = (u >> 17) & 127;
        int pos = base + lst[dl] + atomicAdd(&cnt[dl], 1);
        ssrc[pos] = (int)(u & 0x1FFFFu);
    }
}

// ---------------------------------------------------------------------------
// Kernel A: node transforms, 64-node x 2-matrix blocks (gridDim.y selects
// the pair). LDS = 16.3K xs + 32K ws = 48.3KB -> 3 blocks/CU.
//   y=0: mat0 -> K (fp32),  mat1 -> Qh (bf16)
//   y=1: mat0 -> Vh (bf16), mat1 -> AGG (fp32 + bias B3)
// ---------------------------------------------------------------------------
__global__ __launch_bounds__(256) void transform4_kernel(
    const float* __restrict__ X,
    const float* __restrict__ W0, const float* __restrict__ W1,
    const float* __restrict__ W2, const float* __restrict__ W3,
    const float* __restrict__ B3,
    float* __restrict__ K, ushort_t* __restrict__ Qh,
    ushort_t* __restrict__ Vh, float* __restrict__ AGG)
{
    __shared__ float xs[64][65];
    __shared__ float ws[2][64][64];
    const int tid  = threadIdx.x;
    const int base = blockIdx.x * 64;
    const int pair = blockIdx.y;

    {
        const float* WA = pair ? W2 : W0;
        const float* WB = pair ? W3 : W1;
        float4* dA = (float4*)&ws[0][0][0];
        float4* dB = (float4*)&ws[1][0][0];
        for (int i = tid; i < 1024; i += 256) {
            dA[i] = ((const float4*)WA)[i];
            dB[i] = ((const float4*)WB)[i];
        }
    }
    for (int i = tid; i < 1024; i += 256) {
        int r = i >> 4, c = i & 15;
        int node = base + r;
        float4 v = make_float4(0.f, 0.f, 0.f, 0.f);
        if (node < N_NODES) v = ((const float4*)X)[(size_t)node * 16 + c];
        *(float4*)&xs[r][c * 4] = v;
    }
    __syncthreads();

    const int wid    = tid >> 6;
    const int lane   = tid & 63;
    const int matsel = wid >> 1;                 // wave-uniform: 0 -> WA, 1 -> WB
    const int lg     = ((wid & 1) << 6) | lane;  // 0..127 within matrix
    const int ng     = lg >> 2;                  // 0..31 -> rows 2ng, 2ng+1
    const int og     = (lg & 3) * 16;

    float acc0[16], acc1[16];
    #pragma unroll
    for (int j = 0; j < 16; ++j) { acc0[j] = 0.f; acc1[j] = 0.f; }

    for (int k = 0; k < 64; ++k) {
        float4 wa = *(const float4*)&ws[matsel][k][og + 0];
        float4 wb = *(const float4*)&ws[matsel][k][og + 4];
        float4 wc = *(const float4*)&ws[matsel][k][og + 8];
        float4 wd = *(const float4*)&ws[matsel][k][og + 12];
        float x0 = xs[2 * ng + 0][k];
        float x1 = xs[2 * ng + 1][k];
        FMA16(acc0, x0);
        FMA16(acc1, x1);
    }

    const int kind = pair * 2 + matsel;   // 0:K 1:Qh 2:Vh 3:AGG
    if (kind == 0 || kind == 3) {
        float bias[16];
        #pragma unroll
        for (int j = 0; j < 16; ++j) bias[j] = (kind == 3) ? B3[og + j] : 0.f;
        float* O = (kind == 0) ? K : AGG;
        #pragma unroll
        for (int i = 0; i < 2; ++i) {
            int node = base + 2 * ng + i;
            if (node < N_NODES) {
                float* dst = O + (size_t)node * 64 + og;
                const float* A = (i == 0) ? acc0 : acc1;
                *(float4*)(dst + 0)  = make_float4(A[0]  + bias[0],  A[1]  + bias[1],
                                                   A[2]  + bias[2],  A[3]  + bias[3]);
                *(float4*)(dst + 4)  = make_float4(A[4]  + bias[4],  A[5]  + bias[5],
                                                   A[6]  + bias[6],  A[7]  + bias[7]);
                *(float4*)(dst + 8)  = make_float4(A[8]  + bias[8],  A[9]  + bias[9],
                                                   A[10] + bias[10], A[11] + bias[11]);
                *(float4*)(dst + 12) = make_float4(A[12] + bias[12], A[13] + bias[13],
                                                   A[14] + bias[14], A[15] + bias[15]);
            }
        }
    } else {
        ushort_t* O = (kind == 1) ? Qh : Vh;
        #pragma unroll
        for (int i = 0; i < 2; ++i) {
            int node = base + 2 * ng + i;
            if (node < N_NODES) {
                uint_t* dst = (uint_t*)(O + (size_t)node * 64 + og);
                const float* A = (i == 0) ? acc0 : acc1;
                uint4 u0, u1;
                u0.x = bfpack(A[0],  A[1]);  u0.y = bfpack(A[2],  A[3]);
                u0.z = bfpack(A[4],  A[5]);  u0.w = bfpack(A[6],  A[7]);
                u1.x = bfpack(A[8],  A[9]);  u1.y = bfpack(A[10], A[11]);
                u1.z = bfpack(A[12], A[13]); u1.w = bfpack(A[14], A[15]);
                *(uint4*)(dst + 0) = u0;
                *(uint4*)(dst + 4) = u1;
            }
        }
    }
}

// ---------------------------------------------------------------------------
// Kernel B: atomic-free aggregation, bf16 gathers, fast sigmoid (v_rcp).
// One wave per node; 4 edge slots x 16 column lanes.
// ---------------------------------------------------------------------------
__global__ __launch_bounds__(256) void agg_kernel(
    const float* __restrict__ K, const ushort_t* __restrict__ Qh,
    const ushort_t* __restrict__ Vh, const int* __restrict__ start,
    const int* __restrict__ deg, const int* __restrict__ ssrc,
    float* __restrict__ AGG)
{
    int n = (blockIdx.x * 256 + threadIdx.x) >> 6;   // grid sized exactly
    int lane = threadIdx.x & 63;
    int eg = lane >> 4;            // edge slot 0..3
    int c  = (lane & 15) * 4;      // column group

    const float4 kv = *(const float4*)(K + (size_t)n * 64 + c);
    float4 acc = make_float4(0.f, 0.f, 0.f, 0.f);

    int s0 = start[n];
    int dn = deg[n];
    for (int p = eg; p < dn; p += 4) {
        int s = ssrc[s0 + p];
        ushort4 qh = *(const ushort4*)(Qh + (size_t)s * 64 + c);
        ushort4 vh = *(const ushort4*)(Vh + (size_t)s * 64 + c);
        float ex = __expf(-(kv.x + bf2f(qh.x)));
        float ey = __expf(-(kv.y + bf2f(qh.y)));
        float ez = __expf(-(kv.z + bf2f(qh.z)));
        float ew = __expf(-(kv.w + bf2f(qh.w)));
        acc.x = fmaf(bf2f(vh.x), __builtin_amdgcn_rcpf(1.f + ex), acc.x);
        acc.y = fmaf(bf2f(vh.y), __builtin_amdgcn_rcpf(1.f + ey), acc.y);
        acc.z = fmaf(bf2f(vh.z), __builtin_amdgcn_rcpf(1.f + ez), acc.z);
        acc.w = fmaf(bf2f(vh.w), __builtin_amdgcn_rcpf(1.f + ew), acc.w);
    }

    acc.x += __shfl_xor(acc.x, 16); acc.y += __shfl_xor(acc.y, 16);
    acc.z += __shfl_xor(acc.z, 16); acc.w += __shfl_xor(acc.w, 16);
    acc.x += __shfl_xor(acc.x, 32); acc.y += __shfl_xor(acc.y, 32);
    acc.z += __shfl_xor(acc.z, 32); acc.w += __shfl_xor(acc.w, 32);

    if (eg == 0) {
        float4* a = (float4*)(AGG + (size_t)n * 64 + c);
        float4 o = *a;
        o.x += acc.x; o.y += acc.y; o.z += acc.z; o.w += acc.w;
        *a = o;
    }
}

// ---------------------------------------------------------------------------
// Kernel C: out = relu(agg @ Wl + bl).  33KB LDS -> 4 blocks/CU.
// ---------------------------------------------------------------------------
__global__ __launch_bounds__(256) void relu_gemm_kernel(
    const float* __restrict__ AGG, const float* __restrict__ WL,
    const float* __restrict__ BL, float* __restrict__ OUT)
{
    __shared__ float xin[64][65];
    __shared__ float wl[64][64];
    const int tid  = threadIdx.x;
    const int base = blockIdx.x * 64;

    {
        float4* dl = (float4*)&wl[0][0];
        for (int i = tid; i < 1024; i += 256) dl[i] = ((const float4*)WL)[i];
    }
    for (int i = tid; i < 1024; i += 256) {
        int r = i >> 4, c = i & 15;
        int node = base + r;
        float4 v = make_float4(0.f, 0.f, 0.f, 0.f);
        if (node < N_NODES) v = ((const float4*)AGG)[(size_t)node * 16 + c];
        *(float4*)&xin[r][c * 4] = v;
    }
    __syncthreads();

    const int node = tid >> 2;
    const int og   = (tid & 3) * 16;
    float acc[16];
    #pragma unroll
    for (int j = 0; j < 16; ++j) acc[j] = 0.f;
    for (int k = 0; k < 64; ++k) {
        float4 wa = *(const float4*)&wl[k][og + 0];
        float4 wb = *(const float4*)&wl[k][og + 4];
        float4 wc = *(const float4*)&wl[k][og + 8];
        float4 wd = *(const float4*)&wl[k][og + 12];
        float xv = xin[node][k];
        FMA16(acc, xv);
    }

    int out_node = base + node;
    if (out_node < N_NODES) {
        float* dst = OUT + (size_t)out_node * 64 + og;
        float r0[16];
        #pragma unroll
        for (int j = 0; j < 16; ++j) r0[j] = fmaxf(acc[j] + BL[og + j], 0.f);
        *(float4*)(dst + 0)  = make_float4(r0[0],  r0[1],  r0[2],  r0[3]);
        *(float4*)(dst + 4)  = make_float4(r0[4],  r0[5],  r0[6],  r0[7]);
        *(float4*)(dst + 8)  = make_float4(r0[8],  r0[9],  r0[10], r0[11]);
        *(float4*)(dst + 12) = make_float4(r0[12], r0[13], r0[14], r0[15]);
    }
}

extern "C" void kernel_launch(void* const* d_in, const int* in_sizes, int n_in,
                              void* d_out, int out_size, void* d_ws, size_t ws_size,
                              hipStream_t stream)
{
    const float* x   = (const float*)d_in[0];
    const float* Wk1 = (const float*)d_in[1];
    const float* Wq1 = (const float*)d_in[2];
    const float* Wv1 = (const float*)d_in[3];
    const float* Ws1 = (const float*)d_in[4];
    const float* b1  = (const float*)d_in[5];
    const float* Wl1 = (const float*)d_in[6];
    const float* bl1 = (const float*)d_in[7];
    const float* Wk2 = (const float*)d_in[8];
    const float* Wq2 = (const float*)d_in[9];
    const float* Wv2 = (const float*)d_in[10];
    const float* Ws2 = (const float*)d_in[11];
    const float* b2  = (const float*)d_in[12];
    const float* Wl2 = (const float*)d_in[13];
    const float* bl2 = (const float*)d_in[14];
    const int*   ei  = (const int*)d_in[15];

    const size_t NF = (size_t)N_NODES * 64;
    float*    K     = (float*)d_ws;
    float*    AGG   = K + NF;
    float*    H     = AGG + NF;
    ushort_t* Qh    = (ushort_t*)(H + NF);
    ushort_t* Vh    = Qh + NF;
    int*      hmat  = (int*)(Vh + NF);              // [NBLK_E][NB]
    int*      bbase2 = hmat + NBLK_E * NB;          // 200192, stays aligned
    int*      btot  = bbase2 + 1024;
    int*      deg   = btot + 1024;
    int*      start = deg + 100352;
    int*      ssrc  = start + 100352;
    uint_t*   sbuf  = (uint_t*)(ssrc + N_EDGES);

    // --- CSR build: zero global atomics ---
    hist782_kernel<<<NBLK_E, 256, 0, stream>>>(ei, hmat);
    colscan_kernel<<<1, 1024, 0, stream>>>(hmat, bbase2, btot);
    scat782_kernel<<<NBLK_E, 256, 0, stream>>>(ei, hmat, bbase2, sbuf);
    csr_kernel<<<NB, 256, 0, stream>>>(bbase2, btot, sbuf, deg, start, ssrc);

    // --- Layer 1 ---
    transform4_kernel<<<dim3(1563, 2), 256, 0, stream>>>(x, Wk1, Wq1, Wv1, Ws1, b1,
                                                         K, Qh, Vh, AGG);
    agg_kernel<<<N_NODES / 4, 256, 0, stream>>>(K, Qh, Vh, start, deg, ssrc, AGG);
    relu_gemm_kernel<<<1563, 256, 0, stream>>>(AGG, Wl1, bl1, H);

    // --- Layer 2 ---
    transform4_kernel<<<dim3(1563, 2), 256, 0, stream>>>(H, Wk2, Wq2, Wv2, Ws2, b2,
                                                         K, Qh, Vh, AGG);
    agg_kernel<<<N_NODES / 4, 256, 0, stream>>>(K, Qh, Vh, start, deg, ssrc, AGG);
    relu_gemm_kernel<<<1563, 256, 0, stream>>>(AGG, Wl2, bl2, (float*)d_out);
}

// Round 8
// 468.302 us; speedup vs baseline: 6.5390x; 1.0218x over previous
//
#include <hip/hip_runtime.h>

#define N_NODES 100000
#define N_EDGES 1600000
#define NB      782          // buckets of 128 dst nodes: 782*128 = 100096
#define NBLK_E  256          // edge-pass blocks
#define CHUNK_E 6250         // edges per block: 256*6250 = 1.6M exactly
#define EBUF_CAP 4096        // per-bucket LDS cap (mean 2048, sd ~45)

typedef unsigned short ushort_t;
typedef unsigned int uint_t;

static __device__ __forceinline__ ushort_t bf16_rne(float f) {
    uint_t u = __float_as_uint(f);
    u = (u + 0x7FFFu + ((u >> 16) & 1u)) >> 16;
    return (ushort_t)u;
}
static __device__ __forceinline__ uint_t bfpack(float lo, float hi) {
    return (uint_t)bf16_rne(lo) | ((uint_t)bf16_rne(hi) << 16);
}
static __device__ __forceinline__ float bf2f(ushort_t h) {
    return __uint_as_float(((uint_t)h) << 16);
}

// Accumulate 16 outputs from one x value and four float4 weight chunks.
#define FMA16(A, xv) do { \
    A[0]  = fmaf((xv), wa.x, A[0]);  A[1]  = fmaf((xv), wa.y, A[1]);  \
    A[2]  = fmaf((xv), wa.z, A[2]);  A[3]  = fmaf((xv), wa.w, A[3]);  \
    A[4]  = fmaf((xv), wb.x, A[4]);  A[5]  = fmaf((xv), wb.y, A[5]);  \
    A[6]  = fmaf((xv), wb.z, A[6]);  A[7]  = fmaf((xv), wb.w, A[7]);  \
    A[8]  = fmaf((xv), wc.x, A[8]);  A[9]  = fmaf((xv), wc.y, A[9]);  \
    A[10] = fmaf((xv), wc.z, A[10]); A[11] = fmaf((xv), wc.w, A[11]); \
    A[12] = fmaf((xv), wd.x, A[12]); A[13] = fmaf((xv), wd.y, A[13]); \
    A[14] = fmaf((xv), wd.z, A[14]); A[15] = fmaf((xv), wd.w, A[15]); \
} while (0)

// ---------------------------------------------------------------------------
// CSR build pass A: per-block LDS histogram of dst buckets. NO global atomics.
// ---------------------------------------------------------------------------
__global__ __launch_bounds__(256) void hist782_kernel(
    const int* __restrict__ EI, int* __restrict__ hmat)
{
    __shared__ int h[NB];
    const int tid = threadIdx.x;
    for (int i = tid; i < NB; i += 256) h[i] = 0;
    __syncthreads();
    const int e0 = blockIdx.x * CHUNK_E;
    for (int i = tid; i < CHUNK_E; i += 256) {
        int d = EI[N_EDGES + e0 + i];
        atomicAdd(&h[d >> 7], 1);
    }
    __syncthreads();
    int* row = hmat + blockIdx.x * NB;
    for (int i = tid; i < NB; i += 256) row[i] = h[i];
}

// Pass B: single block. Column-exclusive-scan of hmat[256][782] in place,
// then LDS scan of bucket totals -> bbase2, btot.
__global__ __launch_bounds__(1024) void colscan_kernel(
    int* __restrict__ hmat, int* __restrict__ bbase2, int* __restrict__ btot)
{
    __shared__ int s[1024];
    const int tid = threadIdx.x;
    int run = 0;
    if (tid < NB) {
        for (int blk = 0; blk < NBLK_E; ++blk) {
            int idx = blk * NB + tid;
            int v = hmat[idx];
            hmat[idx] = run;      // exclusive within-bucket prefix
            run += v;
        }
    }
    s[tid] = (tid < NB) ? run : 0;
    __syncthreads();
    for (int off = 1; off < 1024; off <<= 1) {
        int t = (tid >= off) ? s[tid - off] : 0;
        __syncthreads();
        s[tid] += t;
        __syncthreads();
    }
    if (tid < NB) {
        bbase2[tid] = s[tid] - run;   // exclusive across buckets
        btot[tid]   = run;
    }
}

// Pass C: deterministic scatter into bucket-contiguous sbuf. LDS cursors only.
__global__ __launch_bounds__(256) void scat782_kernel(
    const int* __restrict__ EI, const int* __restrict__ hmat,
    const int* __restrict__ bbase2, uint_t* __restrict__ sbuf)
{
    __shared__ int base[NB];
    __shared__ int cur[NB];
    const int tid = threadIdx.x;
    const int* row = hmat + blockIdx.x * NB;
    for (int i = tid; i < NB; i += 256) {
        base[i] = bbase2[i] + row[i];
        cur[i] = 0;
    }
    __syncthreads();
    const int e0 = blockIdx.x * CHUNK_E;
    for (int i = tid; i < CHUNK_E; i += 256) {
        int sN = EI[e0 + i];
        int d  = EI[N_EDGES + e0 + i];
        int b  = d >> 7;
        int p  = base[b] + atomicAdd(&cur[b], 1);
        sbuf[p] = (uint_t)sN | ((uint_t)(d & 127) << 17);
    }
}

// Pass D: one block per bucket -> deg/start/ssrc (dst-sorted).
__global__ __launch_bounds__(256) void csr_kernel(
    const int* __restrict__ bbase2, const int* __restrict__ btot,
    const uint_t* __restrict__ sbuf,
    int* __restrict__ deg, int* __restrict__ start, int* __restrict__ ssrc)
{
    __shared__ uint_t ebuf[EBUF_CAP];
    __shared__ int cnt[128];
    __shared__ int lst[128];
    const int b = blockIdx.x, tid = threadIdx.x;
    const int base = bbase2[b];
    int total = btot[b];
    if (total > EBUF_CAP) total = EBUF_CAP;   // safety clamp

    if (tid < 128) cnt[tid] = 0;
    __syncthreads();

    for (int i = tid; i < total; i += 256) {
        uint_t u = sbuf[base + i];
        ebuf[i] = u;
        atomicAdd(&cnt[(u >> 17) & 127], 1);
    }
    __syncthreads();

    if (tid < 128) lst[tid] = cnt[tid];
    __syncthreads();
    for (int off = 1; off < 128; off <<= 1) {
        int t = (tid < 128 && tid >= off) ? lst[tid - off] : 0;
        __syncthreads();
        if (tid < 128) lst[tid] += t;
        __syncthreads();
    }
    if (tid < 128) {
        lst[tid] -= cnt[tid];              // exclusive
        int n = b * 128 + tid;
        deg[n] = cnt[tid];
        start[n] = base + lst[tid];
        cnt[tid] = 0;                      // reuse as cursor
    }
    __syncthreads();

    for (int i = tid; i < total; i += 256) {
        uint_t u = ebuf[i];
        int dl = (u >> 17) & 127;
        int pos = base + lst[dl] + atomicAdd(&cnt[dl], 1);
        ssrc[pos] = (int)(u & 0x1FFFFu);
    }
}

// ---------------------------------------------------------------------------
// Kernel A: node transforms, 64-node x 2-matrix blocks (gridDim.y = pair).
// LDS 48.3KB -> 3 blocks/CU.
//   y=0: mat0 -> Ek  = exp(-x@Wk)  (fp32)
//        mat1 -> Eqh = exp(-x@Wq)  (bf16)
//   y=1: mat0 -> Vh  = x@Wv        (bf16)
//        mat1 -> AGG = x@Ws + b    (fp32, skip-connection init)
// sigmoid(k+q) = 1/(1 + Ek*Eq): per-edge exp is replaced by one mul.
// ---------------------------------------------------------------------------
__global__ __launch_bounds__(256) void transform4_kernel(
    const float* __restrict__ X,
    const float* __restrict__ W0, const float* __restrict__ W1,
    const float* __restrict__ W2, const float* __restrict__ W3,
    const float* __restrict__ B3,
    float* __restrict__ Ek, ushort_t* __restrict__ Eqh,
    ushort_t* __restrict__ Vh, float* __restrict__ AGG)
{
    __shared__ float xs[64][65];
    __shared__ float ws[2][64][64];
    const int tid  = threadIdx.x;
    const int base = blockIdx.x * 64;
    const int pair = blockIdx.y;

    {
        const float* WA = pair ? W2 : W0;
        const float* WB = pair ? W3 : W1;
        float4* dA = (float4*)&ws[0][0][0];
        float4* dB = (float4*)&ws[1][0][0];
        for (int i = tid; i < 1024; i += 256) {
            dA[i] = ((const float4*)WA)[i];
            dB[i] = ((const float4*)WB)[i];
        }
    }
    for (int i = tid; i < 1024; i += 256) {
        int r = i >> 4, c = i & 15;
        int node = base + r;
        float4 v = make_float4(0.f, 0.f, 0.f, 0.f);
        if (node < N_NODES) v = ((const float4*)X)[(size_t)node * 16 + c];
        *(float4*)&xs[r][c * 4] = v;
    }
    __syncthreads();

    const int wid    = tid >> 6;
    const int lane   = tid & 63;
    const int matsel = wid >> 1;                 // wave-uniform
    const int lg     = ((wid & 1) << 6) | lane;  // 0..127 within matrix
    const int ng     = lg >> 2;                  // 0..31 -> rows 2ng, 2ng+1
    const int og     = (lg & 3) * 16;

    float acc0[16], acc1[16];
    #pragma unroll
    for (int j = 0; j < 16; ++j) { acc0[j] = 0.f; acc1[j] = 0.f; }

    for (int k = 0; k < 64; ++k) {
        float4 wa = *(const float4*)&ws[matsel][k][og + 0];
        float4 wb = *(const float4*)&ws[matsel][k][og + 4];
        float4 wc = *(const float4*)&ws[matsel][k][og + 8];
        float4 wd = *(const float4*)&ws[matsel][k][og + 12];
        float x0 = xs[2 * ng + 0][k];
        float x1 = xs[2 * ng + 1][k];
        FMA16(acc0, x0);
        FMA16(acc1, x1);
    }

    const int kind = pair * 2 + matsel;   // 0:Ek 1:Eqh 2:Vh 3:AGG
    if (kind == 0) {
        #pragma unroll
        for (int i = 0; i < 2; ++i) {
            int node = base + 2 * ng + i;
            if (node < N_NODES) {
                float* dst = Ek + (size_t)node * 64 + og;
                const float* A = (i == 0) ? acc0 : acc1;
                float e[16];
                #pragma unroll
                for (int j = 0; j < 16; ++j) e[j] = __expf(-A[j]);
                *(float4*)(dst + 0)  = make_float4(e[0],  e[1],  e[2],  e[3]);
                *(float4*)(dst + 4)  = make_float4(e[4],  e[5],  e[6],  e[7]);
                *(float4*)(dst + 8)  = make_float4(e[8],  e[9],  e[10], e[11]);
                *(float4*)(dst + 12) = make_float4(e[12], e[13], e[14], e[15]);
            }
        }
    } else if (kind == 3) {
        float bias[16];
        #pragma unroll
        for (int j = 0; j < 16; ++j) bias[j] = B3[og + j];
        #pragma unroll
        for (int i = 0; i < 2; ++i) {
            int node = base + 2 * ng + i;
            if (node < N_NODES) {
                float* dst = AGG + (size_t)node * 64 + og;
                const float* A = (i == 0) ? acc0 : acc1;
                *(float4*)(dst + 0)  = make_float4(A[0]  + bias[0],  A[1]  + bias[1],
                                                   A[2]  + bias[2],  A[3]  + bias[3]);
                *(float4*)(dst + 4)  = make_float4(A[4]  + bias[4],  A[5]  + bias[5],
                                                   A[6]  + bias[6],  A[7]  + bias[7]);
                *(float4*)(dst + 8)  = make_float4(A[8]  + bias[8],  A[9]  + bias[9],
                                                   A[10] + bias[10], A[11] + bias[11]);
                *(float4*)(dst + 12) = make_float4(A[12] + bias[12], A[13] + bias[13],
                                                   A[14] + bias[14], A[15] + bias[15]);
            }
        }
    } else {
        ushort_t* O = (kind == 1) ? Eqh : Vh;
        const bool doexp = (kind == 1);
        #pragma unroll
        for (int i = 0; i < 2; ++i) {
            int node = base + 2 * ng + i;
            if (node < N_NODES) {
                uint_t* dst = (uint_t*)(O + (size_t)node * 64 + og);
                const float* Araw = (i == 0) ? acc0 : acc1;
                float A[16];
                #pragma unroll
                for (int j = 0; j < 16; ++j)
                    A[j] = doexp ? __expf(-Araw[j]) : Araw[j];
                uint4 u0, u1;
                u0.x = bfpack(A[0],  A[1]);  u0.y = bfpack(A[2],  A[3]);
                u0.z = bfpack(A[4],  A[5]);  u0.w = bfpack(A[6],  A[7]);
                u1.x = bfpack(A[8],  A[9]);  u1.y = bfpack(A[10], A[11]);
                u1.z = bfpack(A[12], A[13]); u1.w = bfpack(A[14], A[15]);
                *(uint4*)(dst + 0) = u0;
                *(uint4*)(dst + 4) = u1;
            }
        }
    }
}

// ---------------------------------------------------------------------------
// Kernel B: aggregation. gate = 1/(1 + Ek*Eq) — no per-edge exp.
// One wave per node; 4 edge slots x 16 column lanes.
// ---------------------------------------------------------------------------
__global__ __launch_bounds__(256) void agg_kernel(
    const float* __restrict__ Ek, const ushort_t* __restrict__ Eqh,
    const ushort_t* __restrict__ Vh, const int* __restrict__ start,
    const int* __restrict__ deg, const int* __restrict__ ssrc,
    float* __restrict__ AGG)
{
    int n = (blockIdx.x * 256 + threadIdx.x) >> 6;   // grid sized exactly
    int lane = threadIdx.x & 63;
    int eg = lane >> 4;            // edge slot 0..3
    int c  = (lane & 15) * 4;      // column group

    const float4 ekv = *(const float4*)(Ek + (size_t)n * 64 + c);
    float4 acc = make_float4(0.f, 0.f, 0.f, 0.f);

    int s0 = start[n];
    int dn = deg[n];
    for (int p = eg; p < dn; p += 4) {
        int s = ssrc[s0 + p];
        ushort4 qh = *(const ushort4*)(Eqh + (size_t)s * 64 + c);
        ushort4 vh = *(const ushort4*)(Vh + (size_t)s * 64 + c);
        float tx = fmaf(ekv.x, bf2f(qh.x), 1.f);
        float ty = fmaf(ekv.y, bf2f(qh.y), 1.f);
        float tz = fmaf(ekv.z, bf2f(qh.z), 1.f);
        float tw = fmaf(ekv.w, bf2f(qh.w), 1.f);
        acc.x = fmaf(bf2f(vh.x), __builtin_amdgcn_rcpf(tx), acc.x);
        acc.y = fmaf(bf2f(vh.y), __builtin_amdgcn_rcpf(ty), acc.y);
        acc.z = fmaf(bf2f(vh.z), __builtin_amdgcn_rcpf(tz), acc.z);
        acc.w = fmaf(bf2f(vh.w), __builtin_amdgcn_rcpf(tw), acc.w);
    }

    acc.x += __shfl_xor(acc.x, 16); acc.y += __shfl_xor(acc.y, 16);
    acc.z += __shfl_xor(acc.z, 16); acc.w += __shfl_xor(acc.w, 16);
    acc.x += __shfl_xor(acc.x, 32); acc.y += __shfl_xor(acc.y, 32);
    acc.z += __shfl_xor(acc.z, 32); acc.w += __shfl_xor(acc.w, 32);

    if (eg == 0) {
        float4* a = (float4*)(AGG + (size_t)n * 64 + c);
        float4 o = *a;
        o.x += acc.x; o.y += acc.y; o.z += acc.z; o.w += acc.w;
        *a = o;
    }
}

// ---------------------------------------------------------------------------
// Kernel C: out = relu(agg @ Wl + bl).  33KB LDS -> 4 blocks/CU.
// ---------------------------------------------------------------------------
__global__ __launch_bounds__(256) void relu_gemm_kernel(
    const float* __restrict__ AGG, const float* __restrict__ WL,
    const float* __restrict__ BL, float* __restrict__ OUT)
{
    __shared__ float xin[64][65];
    __shared__ float wl[64][64];
    const int tid  = threadIdx.x;
    const int base = blockIdx.x * 64;

    {
        float4* dl = (float4*)&wl[0][0];
        for (int i = tid; i < 1024; i += 256) dl[i] = ((const float4*)WL)[i];
    }
    for (int i = tid; i < 1024; i += 256) {
        int r = i >> 4, c = i & 15;
        int node = base + r;
        float4 v = make_float4(0.f, 0.f, 0.f, 0.f);
        if (node < N_NODES) v = ((const float4*)AGG)[(size_t)node * 16 + c];
        *(float4*)&xin[r][c * 4] = v;
    }
    __syncthreads();

    const int node = tid >> 2;
    const int og   = (tid & 3) * 16;
    float acc[16];
    #pragma unroll
    for (int j = 0; j < 16; ++j) acc[j] = 0.f;
    for (int k = 0; k < 64; ++k) {
        float4 wa = *(const float4*)&wl[k][og + 0];
        float4 wb = *(const float4*)&wl[k][og + 4];
        float4 wc = *(const float4*)&wl[k][og + 8];
        float4 wd = *(const float4*)&wl[k][og + 12];
        float xv = xin[node][k];
        FMA16(acc, xv);
    }

    int out_node = base + node;
    if (out_node < N_NODES) {
        float* dst = OUT + (size_t)out_node * 64 + og;
        float r0[16];
        #pragma unroll
        for (int j = 0; j < 16; ++j) r0[j] = fmaxf(acc[j] + BL[og + j], 0.f);
        *(float4*)(dst + 0)  = make_float4(r0[0],  r0[1],  r0[2],  r0[3]);
        *(float4*)(dst + 4)  = make_float4(r0[4],  r0[5],  r0[6],  r0[7]);
        *(float4*)(dst + 8)  = make_float4(r0[8],  r0[9],  r0[10], r0[11]);
        *(float4*)(dst + 12) = make_float4(r0[12], r0[13], r0[14], r0[15]);
    }
}

extern "C" void kernel_launch(void* const* d_in, const int* in_sizes, int n_in,
                              void* d_out, int out_size, void* d_ws, size_t ws_size,
                              hipStream_t stream)
{
    const float* x   = (const float*)d_in[0];
    const float* Wk1 = (const float*)d_in[1];
    const float* Wq1 = (const float*)d_in[2];
    const float* Wv1 = (const float*)d_in[3];
    const float* Ws1 = (const float*)d_in[4];
    const float* b1  = (const float*)d_in[5];
    const float* Wl1 = (const float*)d_in[6];
    const float* bl1 = (const float*)d_in[7];
    const float* Wk2 = (const float*)d_in[8];
    const float* Wq2 = (const float*)d_in[9];
    const float* Wv2 = (const float*)d_in[10];
    const float* Ws2 = (const float*)d_in[11];
    const float* b2  = (const float*)d_in[12];
    const float* Wl2 = (const float*)d_in[13];
    const float* bl2 = (const float*)d_in[14];
    const int*   ei  = (const int*)d_in[15];

    const size_t NF = (size_t)N_NODES * 64;
    float*    Ek    = (float*)d_ws;
    float*    AGG   = Ek + NF;
    float*    H     = AGG + NF;
    ushort_t* Eqh   = (ushort_t*)(H + NF);
    ushort_t* Vh    = Eqh + NF;
    int*      hmat  = (int*)(Vh + NF);              // [NBLK_E][NB]
    int*      bbase2 = hmat + NBLK_E * NB;
    int*      btot  = bbase2 + 1024;
    int*      deg   = btot + 1024;
    int*      start = deg + 100352;
    int*      ssrc  = start + 100352;
    uint_t*   sbuf  = (uint_t*)(ssrc + N_EDGES);

    // --- CSR build: zero global atomics ---
    hist782_kernel<<<NBLK_E, 256, 0, stream>>>(ei, hmat);
    colscan_kernel<<<1, 1024, 0, stream>>>(hmat, bbase2, btot);
    scat782_kernel<<<NBLK_E, 256, 0, stream>>>(ei, hmat, bbase2, sbuf);
    csr_kernel<<<NB, 256, 0, stream>>>(bbase2, btot, sbuf, deg, start, ssrc);

    // --- Layer 1 ---
    transform4_kernel<<<dim3(1563, 2), 256, 0, stream>>>(x, Wk1, Wq1, Wv1, Ws1, b1,
                                                         Ek, Eqh, Vh, AGG);
    agg_kernel<<<N_NODES / 4, 256, 0, stream>>>(Ek, Eqh, Vh, start, deg, ssrc, AGG);
    relu_gemm_kernel<<<1563, 256, 0, stream>>>(AGG, Wl1, bl1, H);

    // --- Layer 2 ---
    transform4_kernel<<<dim3(1563, 2), 256, 0, stream>>>(H, Wk2, Wq2, Wv2, Ws2, b2,
                                                         Ek, Eqh, Vh, AGG);
    agg_kernel<<<N_NODES / 4, 256, 0, stream>>>(Ek, Eqh, Vh, start, deg, ssrc, AGG);
    relu_gemm_kernel<<<1563, 256, 0, stream>>>(AGG, Wl2, bl2, (float*)d_out);
}

// Round 11
// 438.032 us; speedup vs baseline: 6.9909x; 1.0691x over previous
//
#include <hip/hip_runtime.h>

#define N_NODES 100000
#define N_EDGES 1600000
#define NB      782          // buckets of 128 dst nodes: 782*128 = 100096
#define NBLK_E  256          // edge-pass blocks
#define CHUNK_E 6250         // edges per block: 256*6250 = 1.6M exactly
#define EBUF_CAP 4096        // per-bucket LDS cap (mean 2048, sd ~45)

typedef unsigned short ushort_t;
typedef unsigned int uint_t;

static __device__ __forceinline__ ushort_t bf16_rne(float f) {
    uint_t u = __float_as_uint(f);
    u = (u + 0x7FFFu + ((u >> 16) & 1u)) >> 16;
    return (ushort_t)u;
}
static __device__ __forceinline__ uint_t bfpack(float lo, float hi) {
    return (uint_t)bf16_rne(lo) | ((uint_t)bf16_rne(hi) << 16);
}
static __device__ __forceinline__ float bf2f(ushort_t h) {
    return __uint_as_float(((uint_t)h) << 16);
}
// unpack packed bf16 pair from a uint: lo = bits[15:0], hi = bits[31:16]
static __device__ __forceinline__ void bf2x2(uint_t u, float& lo, float& hi) {
    lo = __uint_as_float(u << 16);
    hi = __uint_as_float(u & 0xFFFF0000u);
}

// Accumulate 16 outputs from one x value and four float4 weight chunks.
#define FMA16(A, xv) do { \
    A[0]  = fmaf((xv), wa.x, A[0]);  A[1]  = fmaf((xv), wa.y, A[1]);  \
    A[2]  = fmaf((xv), wa.z, A[2]);  A[3]  = fmaf((xv), wa.w, A[3]);  \
    A[4]  = fmaf((xv), wb.x, A[4]);  A[5]  = fmaf((xv), wb.y, A[5]);  \
    A[6]  = fmaf((xv), wb.z, A[6]);  A[7]  = fmaf((xv), wb.w, A[7]);  \
    A[8]  = fmaf((xv), wc.x, A[8]);  A[9]  = fmaf((xv), wc.y, A[9]);  \
    A[10] = fmaf((xv), wc.z, A[10]); A[11] = fmaf((xv), wc.w, A[11]); \
    A[12] = fmaf((xv), wd.x, A[12]); A[13] = fmaf((xv), wd.y, A[13]); \
    A[14] = fmaf((xv), wd.z, A[14]); A[15] = fmaf((xv), wd.w, A[15]); \
} while (0)

// ---------------------------------------------------------------------------
// CSR build pass A: per-block LDS histogram; TRANSPOSED write hmat_t[b][blk].
// ---------------------------------------------------------------------------
__global__ __launch_bounds__(256) void hist782_kernel(
    const int* __restrict__ EI, int* __restrict__ hmat_t)
{
    __shared__ int h[NB];
    const int tid = threadIdx.x;
    for (int i = tid; i < NB; i += 256) h[i] = 0;
    __syncthreads();
    const int e0 = blockIdx.x * CHUNK_E;
    for (int i = tid; i < CHUNK_E; i += 256) {
        int d = EI[N_EDGES + e0 + i];
        atomicAdd(&h[d >> 7], 1);
    }
    __syncthreads();
    for (int i = tid; i < NB; i += 256)
        hmat_t[i * NBLK_E + blockIdx.x] = h[i];
}

// Pass B1: per-bucket wave scan over the 256 block-counts.
__global__ __launch_bounds__(256) void colscan_p1_kernel(
    int* __restrict__ hmat_t, int* __restrict__ btot)
{
    const int b = blockIdx.x * 4 + (threadIdx.x >> 6);
    if (b >= NB) return;
    const int lane = threadIdx.x & 63;
    int4 v = ((int4*)(hmat_t + b * NBLK_E))[lane];
    const int tot = v.x + v.y + v.z + v.w;
    int x = tot;
    #pragma unroll
    for (int off = 1; off < 64; off <<= 1) {
        int t = __shfl_up(x, off);
        if (lane >= off) x += t;
    }
    const int base = x - tot;
    int4 o;
    o.x = base;
    o.y = base + v.x;
    o.z = base + v.x + v.y;
    o.w = base + v.x + v.y + v.z;
    ((int4*)(hmat_t + b * NBLK_E))[lane] = o;
    if (lane == 63) btot[b] = x;
}

// Pass B2: single-block exclusive scan of the 782 bucket totals -> bbase2.
__global__ __launch_bounds__(1024) void colscan_p2_kernel(
    const int* __restrict__ btot, int* __restrict__ bbase2)
{
    __shared__ int s[1024];
    const int tid = threadIdx.x;
    int v = (tid < NB) ? btot[tid] : 0;
    s[tid] = v;
    __syncthreads();
    for (int off = 1; off < 1024; off <<= 1) {
        int t = (tid >= off) ? s[tid - off] : 0;
        __syncthreads();
        s[tid] += t;
        __syncthreads();
    }
    if (tid < NB) bbase2[tid] = s[tid] - v;
}

// Pass C: deterministic scatter into bucket-contiguous sbuf. LDS cursors only.
__global__ __launch_bounds__(256) void scat782_kernel(
    const int* __restrict__ EI, const int* __restrict__ hmat_t,
    const int* __restrict__ bbase2, uint_t* __restrict__ sbuf)
{
    __shared__ int base[NB];
    __shared__ int cur[NB];
    const int tid = threadIdx.x;
    for (int i = tid; i < NB; i += 256) {
        base[i] = bbase2[i] + hmat_t[i * NBLK_E + blockIdx.x];
        cur[i] = 0;
    }
    __syncthreads();
    const int e0 = blockIdx.x * CHUNK_E;
    for (int i = tid; i < CHUNK_E; i += 256) {
        int sN = EI[e0 + i];
        int d  = EI[N_EDGES + e0 + i];
        int b  = d >> 7;
        int p  = base[b] + atomicAdd(&cur[b], 1);
        sbuf[p] = (uint_t)sN | ((uint_t)(d & 127) << 17);
    }
}

// Pass D: one block per bucket -> deg/start/ssrc (dst-sorted).
__global__ __launch_bounds__(256) void csr_kernel(
    const int* __restrict__ bbase2, const int* __restrict__ btot,
    const uint_t* __restrict__ sbuf,
    int* __restrict__ deg, int* __restrict__ start, int* __restrict__ ssrc)
{
    __shared__ uint_t ebuf[EBUF_CAP];
    __shared__ int cnt[128];
    __shared__ int lst[128];
    const int b = blockIdx.x, tid = threadIdx.x;
    const int base = bbase2[b];
    int total = btot[b];
    if (total > EBUF_CAP) total = EBUF_CAP;   // safety clamp

    if (tid < 128) cnt[tid] = 0;
    __syncthreads();

    for (int i = tid; i < total; i += 256) {
        uint_t u = sbuf[base + i];
        ebuf[i] = u;
        atomicAdd(&cnt[(u >> 17) & 127], 1);
    }
    __syncthreads();

    if (tid < 128) lst[tid] = cnt[tid];
    __syncthreads();
    for (int off = 1; off < 128; off <<= 1) {
        int t = (tid < 128 && tid >= off) ? lst[tid - off] : 0;
        __syncthreads();
        if (tid < 128) lst[tid] += t;
        __syncthreads();
    }
    if (tid < 128) {
        lst[tid] -= cnt[tid];              // exclusive
        int n = b * 128 + tid;
        deg[n] = cnt[tid];
        start[n] = base + lst[tid];
        cnt[tid] = 0;                      // reuse as cursor
    }
    __syncthreads();

    for (int i = tid; i < total; i += 256) {
        uint_t u = ebuf[i];
        int dl = (u >> 17) & 127;
        int pos = base + lst[dl] + atomicAdd(&cnt[dl], 1);
        ssrc[pos] = (int)(u & 0x1FFFFu);
    }
}

// ---------------------------------------------------------------------------
// Kernel A: node transforms, 64-node x 2-matrix blocks (gridDim.y = pair).
// LDS 48.3KB -> 3 blocks/CU.
//   y=0: mat0 -> Ekh = exp(-x@Wk)  (bf16)
//        mat1 -> Eqh = exp(-x@Wq)  (bf16)
//   y=1: mat0 -> Vh  = x@Wv        (bf16)
//        mat1 -> AGG = x@Ws + b    (fp32, skip-connection init)
// sigmoid(k+q) = 1/(1 + Ekh*Eqh): per-edge exp replaced by one mul.
// (fp8 for Eq was tried and FAILED: e4m3 max 448 < exp(8.5) tail -> gate
//  error O(0.5). bf16's 8-bit exponent is required here.)
// ---------------------------------------------------------------------------
__global__ __launch_bounds__(256) void transform4_kernel(
    const float* __restrict__ X,
    const float* __restrict__ W0, const float* __restrict__ W1,
    const float* __restrict__ W2, const float* __restrict__ W3,
    const float* __restrict__ B3,
    ushort_t* __restrict__ Ekh, ushort_t* __restrict__ Eqh,
    ushort_t* __restrict__ Vh, float* __restrict__ AGG)
{
    __shared__ float xs[64][65];
    __shared__ float ws[2][64][64];
    const int tid  = threadIdx.x;
    const int base = blockIdx.x * 64;
    const int pair = blockIdx.y;

    {
        const float* WA = pair ? W2 : W0;
        const float* WB = pair ? W3 : W1;
        float4* dA = (float4*)&ws[0][0][0];
        float4* dB = (float4*)&ws[1][0][0];
        for (int i = tid; i < 1024; i += 256) {
            dA[i] = ((const float4*)WA)[i];
            dB[i] = ((const float4*)WB)[i];
        }
    }
    for (int i = tid; i < 1024; i += 256) {
        int r = i >> 4, c = i & 15;
        int node = base + r;
        float4 v = make_float4(0.f, 0.f, 0.f, 0.f);
        if (node < N_NODES) v = ((const float4*)X)[(size_t)node * 16 + c];
        *(float4*)&xs[r][c * 4] = v;
    }
    __syncthreads();

    const int wid    = tid >> 6;
    const int lane   = tid & 63;
    const int matsel = wid >> 1;                 // wave-uniform
    const int lg     = ((wid & 1) << 6) | lane;  // 0..127 within matrix
    const int ng     = lg >> 2;                  // 0..31 -> rows 2ng, 2ng+1
    const int og     = (lg & 3) * 16;

    float acc0[16], acc1[16];
    #pragma unroll
    for (int j = 0; j < 16; ++j) { acc0[j] = 0.f; acc1[j] = 0.f; }

    for (int k = 0; k < 64; ++k) {
        float4 wa = *(const float4*)&ws[matsel][k][og + 0];
        float4 wb = *(const float4*)&ws[matsel][k][og + 4];
        float4 wc = *(const float4*)&ws[matsel][k][og + 8];
        float4 wd = *(const float4*)&ws[matsel][k][og + 12];
        float x0 = xs[2 * ng + 0][k];
        float x1 = xs[2 * ng + 1][k];
        FMA16(acc0, x0);
        FMA16(acc1, x1);
    }

    const int kind = pair * 2 + matsel;   // 0:Ekh 1:Eqh 2:Vh 3:AGG
    if (kind == 3) {
        float bias[16];
        #pragma unroll
        for (int j = 0; j < 16; ++j) bias[j] = B3[og + j];
        #pragma unroll
        for (int i = 0; i < 2; ++i) {
            int node = base + 2 * ng + i;
            if (node < N_NODES) {
                float* dst = AGG + (size_t)node * 64 + og;
                const float* A = (i == 0) ? acc0 : acc1;
                *(float4*)(dst + 0)  = make_float4(A[0]  + bias[0],  A[1]  + bias[1],
                                                   A[2]  + bias[2],  A[3]  + bias[3]);
                *(float4*)(dst + 4)  = make_float4(A[4]  + bias[4],  A[5]  + bias[5],
                                                   A[6]  + bias[6],  A[7]  + bias[7]);
                *(float4*)(dst + 8)  = make_float4(A[8]  + bias[8],  A[9]  + bias[9],
                                                   A[10] + bias[10], A[11] + bias[11]);
                *(float4*)(dst + 12) = make_float4(A[12] + bias[12], A[13] + bias[13],
                                                   A[14] + bias[14], A[15] + bias[15]);
            }
        }
    } else {
        // bf16 pack: kinds 0,1 -> exp(-acc); kind 2 -> raw v
        ushort_t* O = (kind == 0) ? Ekh : (kind == 1) ? Eqh : Vh;
        const bool doexp = (kind < 2);
        #pragma unroll
        for (int i = 0; i < 2; ++i) {
            int node = base + 2 * ng + i;
            if (node < N_NODES) {
                uint_t* dst = (uint_t*)(O + (size_t)node * 64 + og);
                const float* Araw = (i == 0) ? acc0 : acc1;
                float A[16];
                #pragma unroll
                for (int j = 0; j < 16; ++j)
                    A[j] = doexp ? __expf(-Araw[j]) : Araw[j];
                uint4 u0, u1;
                u0.x = bfpack(A[0],  A[1]);  u0.y = bfpack(A[2],  A[3]);
                u0.z = bfpack(A[4],  A[5]);  u0.w = bfpack(A[6],  A[7]);
                u1.x = bfpack(A[8],  A[9]);  u1.y = bfpack(A[10], A[11]);
                u1.z = bfpack(A[12], A[13]); u1.w = bfpack(A[14], A[15]);
                *(uint4*)(dst + 0) = u0;
                *(uint4*)(dst + 4) = u1;
            }
        }
    }
}

// ---------------------------------------------------------------------------
// Kernel B: aggregation. gate = 1/(1 + Ek*Eq), all-bf16 gathers.
// One wave per node; 8 edge slots x 8 column lanes x 16B — doubles the
// outstanding gathers per wave vs the 4x16 layout (latency hiding), same
// bytes, full-row coalescing (8 lanes x 16B = 128B row).
// ---------------------------------------------------------------------------
__global__ __launch_bounds__(256) void agg_kernel(
    const ushort_t* __restrict__ Ekh, const ushort_t* __restrict__ Eqh,
    const ushort_t* __restrict__ Vh, const int* __restrict__ start,
    const int* __restrict__ deg, const int* __restrict__ ssrc,
    float* __restrict__ AGG)
{
    int n = (blockIdx.x * 256 + threadIdx.x) >> 6;   // grid sized exactly
    int lane = threadIdx.x & 63;
    int eg = lane >> 3;            // edge slot 0..7
    int c8 = (lane & 7) * 8;       // column octet base

    // Ek for this lane's 8 columns
    uint4 eku = *(const uint4*)(Ekh + (size_t)n * 64 + c8);
    float ek[8];
    bf2x2(eku.x, ek[0], ek[1]); bf2x2(eku.y, ek[2], ek[3]);
    bf2x2(eku.z, ek[4], ek[5]); bf2x2(eku.w, ek[6], ek[7]);

    float acc[8];
    #pragma unroll
    for (int j = 0; j < 8; ++j) acc[j] = 0.f;

    int s0 = start[n];
    int dn = deg[n];
    for (int p = eg; p < dn; p += 8) {
        int s = ssrc[s0 + p];
        uint4 qu = *(const uint4*)(Eqh + (size_t)s * 64 + c8);
        uint4 vu = *(const uint4*)(Vh  + (size_t)s * 64 + c8);
        float q[8], v[8];
        bf2x2(qu.x, q[0], q[1]); bf2x2(qu.y, q[2], q[3]);
        bf2x2(qu.z, q[4], q[5]); bf2x2(qu.w, q[6], q[7]);
        bf2x2(vu.x, v[0], v[1]); bf2x2(vu.y, v[2], v[3]);
        bf2x2(vu.z, v[4], v[5]); bf2x2(vu.w, v[6], v[7]);
        #pragma unroll
        for (int j = 0; j < 8; ++j) {
            float t = fmaf(ek[j], q[j], 1.f);
            acc[j] = fmaf(v[j], __builtin_amdgcn_rcpf(t), acc[j]);
        }
    }

    // reduce across the 8 edge slots (lanes differing in bits 3,4,5)
    #pragma unroll
    for (int j = 0; j < 8; ++j) {
        acc[j] += __shfl_xor(acc[j], 8);
        acc[j] += __shfl_xor(acc[j], 16);
        acc[j] += __shfl_xor(acc[j], 32);
    }

    if (eg == 0) {
        float* a = AGG + (size_t)n * 64 + c8;
        float4 o0 = *(float4*)(a + 0);
        float4 o1 = *(float4*)(a + 4);
        o0.x += acc[0]; o0.y += acc[1]; o0.z += acc[2]; o0.w += acc[3];
        o1.x += acc[4]; o1.y += acc[5]; o1.z += acc[6]; o1.w += acc[7];
        *(float4*)(a + 0) = o0;
        *(float4*)(a + 4) = o1;
    }
}

// ---------------------------------------------------------------------------
// Kernel C: out = relu(agg @ Wl + bl).  33KB LDS -> 4 blocks/CU.
// ---------------------------------------------------------------------------
__global__ __launch_bounds__(256) void relu_gemm_kernel(
    const float* __restrict__ AGG, const float* __restrict__ WL,
    const float* __restrict__ BL, float* __restrict__ OUT)
{
    __shared__ float xin[64][65];
    __shared__ float wl[64][64];
    const int tid  = threadIdx.x;
    const int base = blockIdx.x * 64;

    {
        float4* dl = (float4*)&wl[0][0];
        for (int i = tid; i < 1024; i += 256) dl[i] = ((const float4*)WL)[i];
    }
    for (int i = tid; i < 1024; i += 256) {
        int r = i >> 4, c = i & 15;
        int node = base + r;
        float4 v = make_float4(0.f, 0.f, 0.f, 0.f);
        if (node < N_NODES) v = ((const float4*)AGG)[(size_t)node * 16 + c];
        *(float4*)&xin[r][c * 4] = v;
    }
    __syncthreads();

    const int node = tid >> 2;
    const int og   = (tid & 3) * 16;
    float acc[16];
    #pragma unroll
    for (int j = 0; j < 16; ++j) acc[j] = 0.f;
    for (int k = 0; k < 64; ++k) {
        float4 wa = *(const float4*)&wl[k][og + 0];
        float4 wb = *(const float4*)&wl[k][og + 4];
        float4 wc = *(const float4*)&wl[k][og + 8];
        float4 wd = *(const float4*)&wl[k][og + 12];
        float xv = xin[node][k];
        FMA16(acc, xv);
    }

    int out_node = base + node;
    if (out_node < N_NODES) {
        float* dst = OUT + (size_t)out_node * 64 + og;
        float r0[16];
        #pragma unroll
        for (int j = 0; j < 16; ++j) r0[j] = fmaxf(acc[j] + BL[og + j], 0.f);
        *(float4*)(dst + 0)  = make_float4(r0[0],  r0[1],  r0[2],  r0[3]);
        *(float4*)(dst + 4)  = make_float4(r0[4],  r0[5],  r0[6],  r0[7]);
        *(float4*)(dst + 8)  = make_float4(r0[8],  r0[9],  r0[10], r0[11]);
        *(float4*)(dst + 12) = make_float4(r0[12], r0[13], r0[14], r0[15]);
    }
}

extern "C" void kernel_launch(void* const* d_in, const int* in_sizes, int n_in,
                              void* d_out, int out_size, void* d_ws, size_t ws_size,
                              hipStream_t stream)
{
    const float* x   = (const float*)d_in[0];
    const float* Wk1 = (const float*)d_in[1];
    const float* Wq1 = (const float*)d_in[2];
    const float* Wv1 = (const float*)d_in[3];
    const float* Ws1 = (const float*)d_in[4];
    const float* b1  = (const float*)d_in[5];
    const float* Wl1 = (const float*)d_in[6];
    const float* bl1 = (const float*)d_in[7];
    const float* Wk2 = (const float*)d_in[8];
    const float* Wq2 = (const float*)d_in[9];
    const float* Wv2 = (const float*)d_in[10];
    const float* Ws2 = (const float*)d_in[11];
    const float* b2  = (const float*)d_in[12];
    const float* Wl2 = (const float*)d_in[13];
    const float* bl2 = (const float*)d_in[14];
    const int*   ei  = (const int*)d_in[15];

    const size_t NF = (size_t)N_NODES * 64;
    float*    AGG   = (float*)d_ws;
    float*    H     = AGG + NF;
    ushort_t* Ekh   = (ushort_t*)(H + NF);
    ushort_t* Eqh   = Ekh + NF;
    ushort_t* Vh    = Eqh + NF;
    int*      hmat_t = (int*)(Vh + NF);             // [NB][NBLK_E] transposed
    int*      btot   = hmat_t + NB * NBLK_E;
    int*      bbase2 = btot + 1024;
    int*      deg    = bbase2 + 1024;
    int*      start  = deg + 100352;
    int*      ssrc   = start + 100352;
    uint_t*   sbuf   = (uint_t*)(ssrc + N_EDGES);

    // --- CSR build: zero global atomics, parallel scan ---
    hist782_kernel<<<NBLK_E, 256, 0, stream>>>(ei, hmat_t);
    colscan_p1_kernel<<<(NB + 3) / 4, 256, 0, stream>>>(hmat_t, btot);
    colscan_p2_kernel<<<1, 1024, 0, stream>>>(btot, bbase2);
    scat782_kernel<<<NBLK_E, 256, 0, stream>>>(ei, hmat_t, bbase2, sbuf);
    csr_kernel<<<NB, 256, 0, stream>>>(bbase2, btot, sbuf, deg, start, ssrc);

    // --- Layer 1 ---
    transform4_kernel<<<dim3(1563, 2), 256, 0, stream>>>(x, Wk1, Wq1, Wv1, Ws1, b1,
                                                         Ekh, Eqh, Vh, AGG);
    agg_kernel<<<N_NODES / 4, 256, 0, stream>>>(Ekh, Eqh, Vh, start, deg, ssrc, AGG);
    relu_gemm_kernel<<<1563, 256, 0, stream>>>(AGG, Wl1, bl1, H);

    // --- Layer 2 ---
    transform4_kernel<<<dim3(1563, 2), 256, 0, stream>>>(H, Wk2, Wq2, Wv2, Ws2, b2,
                                                         Ekh, Eqh, Vh, AGG);
    agg_kernel<<<N_NODES / 4, 256, 0, stream>>>(Ekh, Eqh, Vh, start, deg, ssrc, AGG);
    relu_gemm_kernel<<<1563, 256, 0, stream>>>(AGG, Wl2, bl2, (float*)d_out);
}